// Round 1
// 327.776 us; speedup vs baseline: 1.0294x; 1.0294x over previous
//
#include <hip/hip_runtime.h>

#define MDIM 1024
#define FFH  2048
#define SEQ  2048
#define AST  72    // Ks row stride (shorts): 144 B, 16B multiple (16B alignment mandatory: R6/R7)
#define VST  136   // Vt/PQs row stride (128 keys + 8 pad): 272 B, 16B multiple; same bank class as 72
#define QSCL 0.18033688f   // 0.125 * log2(e): scores exit MFMA in log2 domain -> raw v_exp_f32

// exp2f libcall carries a denormal-fixup sequence (R10: attn VALUBusy 46.8->55.6, +9us).
#if __has_builtin(__builtin_amdgcn_exp2f)
  #define EXP2(x) __builtin_amdgcn_exp2f(x)
#else
  #define EXP2(x) exp2f(x)
#endif

typedef __attribute__((ext_vector_type(8))) __bf16 bf16x8;
typedef __attribute__((ext_vector_type(4))) float floatx4;
typedef __attribute__((address_space(3))) unsigned int lds_uint;
typedef const __attribute__((address_space(1))) unsigned int g_uint;

__device__ __forceinline__ unsigned short f2bf(float f){
  union { float f; unsigned u; } v; v.f = f;
  unsigned u = v.u;
  u += 0x7fffu + ((u >> 16) & 1u);
  return (unsigned short)(u >> 16);
}
__device__ __forceinline__ unsigned short f2bf_tr(float f){   // truncating (P >= 0, softmax-internal)
  union { float f; unsigned u; } v; v.f = f;
  return (unsigned short)(v.u >> 16);
}

// ---------------- prep kernel 1: x -> bf16 (blocks 0..4095) + qbias build (blocks 4096..4107) ----------------
__global__ void k_cvt_qb(const float* __restrict__ x, unsigned short* __restrict__ xb,
                         const float* __restrict__ bq, const float* __restrict__ bk,
                         const float* __restrict__ bv, float* __restrict__ qbias){
  const int bid = blockIdx.x, t = threadIdx.x;
  if (bid < 4096){
    int i = (bid * 256 + t) * 4;
    float4 v = *(const float4*)(x + i);
    ushort4 o;
    o.x = f2bf(v.x); o.y = f2bf(v.y); o.z = f2bf(v.z); o.w = f2bf(v.w);
    *(ushort4*)(xb + i) = o;
  } else {
    int i = (bid - 4096) * 256 + t;   // 0..3071
    qbias[i] = (i < 1024) ? bq[i] * QSCL : (i < 2048) ? bk[i - 1024] : bv[i - 2048];
  }
}

// ---------------- prep kernel 2: all weight transposes (block-uniform branches) ----------------
// bid <1024: Wo[1024][1024]->wot | <3072: W1[1024][2048]->w1t | <5120: W2[2048][1024]->w2t
// | <8192: Wq/Wk/Wv [16][1024][64] -> fused wqkvt [3072][1024] (Wq pre-scaled QSCL)
__global__ void __launch_bounds__(256) k_prep_w(const float* __restrict__ Wo, const float* __restrict__ W1,
                                                const float* __restrict__ W2, const float* __restrict__ Wq,
                                                const float* __restrict__ Wk, const float* __restrict__ Wv,
                                                unsigned short* __restrict__ wot, unsigned short* __restrict__ w1t,
                                                unsigned short* __restrict__ w2t, unsigned short* __restrict__ wqkvt){
  __shared__ unsigned short Ts[32 * 36];
  const int t = threadIdx.x, bid = blockIdx.x;
  const int lr = t >> 3, lc4 = (t & 7) << 2;
  if (bid >= 5120){
    const int id = bid - 5120;                  // [0,3072)
    const int xm = id & 31, yd = (id >> 5) & 1, z = id >> 6;   // z in [0,48)
    const int tensor = z >> 4, h = z & 15;
    const float* W = (tensor == 0) ? Wq : (tensor == 1) ? Wk : Wv;
    const float scl = (tensor == 0) ? QSCL : 1.0f;
    const int m0 = xm << 5, d0 = yd << 5;
    float4 v = *(const float4*)(W + ((size_t)h << 16) + (size_t)(m0 + lr) * 64 + d0 + lc4);
    ushort4 o; o.x = f2bf(v.x * scl); o.y = f2bf(v.y * scl); o.z = f2bf(v.z * scl); o.w = f2bf(v.w * scl);
    *(ushort4*)&Ts[lr * 36 + lc4] = o;
    __syncthreads();
    ushort4 w;
    w.x = Ts[(lc4 + 0) * 36 + lr];
    w.y = Ts[(lc4 + 1) * 36 + lr];
    w.z = Ts[(lc4 + 2) * 36 + lr];
    w.w = Ts[(lc4 + 3) * 36 + lr];
    const int n = (tensor << 10) + (h << 6) + d0 + lr;
    *(ushort4*)(wqkvt + ((size_t)n << 10) + m0 + lc4) = w;
    return;
  }
  const float* src; unsigned short* dst; int K, N, k0, n0;
  if (bid < 1024){
    src = Wo; dst = wot; K = 1024; N = 1024;
    n0 = (bid & 31) << 5; k0 = (bid >> 5) << 5;
  } else if (bid < 3072){
    const int id = bid - 1024;
    src = W1; dst = w1t; K = 1024; N = 2048;
    n0 = (id & 63) << 5; k0 = (id >> 6) << 5;
  } else {
    const int id = bid - 3072;
    src = W2; dst = w2t; K = 2048; N = 1024;
    n0 = (id & 31) << 5; k0 = (id >> 5) << 5;
  }
  float4 v = *(const float4*)(src + (size_t)(k0 + lr) * N + n0 + lc4);
  ushort4 o; o.x = f2bf(v.x); o.y = f2bf(v.y); o.z = f2bf(v.z); o.w = f2bf(v.w);
  *(ushort4*)&Ts[lr * 36 + lc4] = o;
  __syncthreads();
  ushort4 w;
  w.x = Ts[(lc4 + 0) * 36 + lr];
  w.y = Ts[(lc4 + 1) * 36 + lr];
  w.z = Ts[(lc4 + 2) * 36 + lr];
  w.w = Ts[(lc4 + 3) * 36 + lr];
  *(ushort4*)(dst + (size_t)(n0 + lr) * K + k0 + lc4) = w;
}

// ---------------- bf16 MFMA GEMM, 128x128 tile, BK=64 (two [128][32] sub-buffers) ----------------
template<int RELU, int OUTBF>
__global__ void __launch_bounds__(256) k_gemm128(const unsigned short* __restrict__ A,
                                                 const unsigned short* __restrict__ Bt,
                                                 const float* __restrict__ bias,
                                                 void* __restrict__ Cout, int N, int K){
  __shared__ unsigned short As[2 * 128 * 32];
  __shared__ unsigned short Bs[2 * 128 * 32];
  const int t = threadIdx.x;
  const int m0 = blockIdx.y << 7, n0 = blockIdx.x << 7;
  const int lane = t & 63, w = t >> 6;
  const int quad = lane >> 4, l16 = lane & 15;
  const int mw = (w & 1) << 6, nw = (w >> 1) << 6;
  floatx4 acc[4][4];
  #pragma unroll
  for (int i = 0; i < 4; i++)
    #pragma unroll
    for (int j = 0; j < 4; j++) acc[i][j] = (floatx4){0.f, 0.f, 0.f, 0.f};
  const unsigned short* Ag  = A  + (size_t)(m0 + (t >> 2)) * K + ((t & 3) << 3);
  const unsigned short* Ag2 = Ag + (size_t)64 * K;
  const unsigned short* Bg  = Bt + (size_t)(n0 + (t >> 2)) * K + ((t & 3) << 3);
  const unsigned short* Bg2 = Bg + (size_t)64 * K;
  for (int kb = 0; kb < K; kb += 64){
    #pragma unroll
    for (int s = 0; s < 2; s++){
      const int ko = kb + (s << 5), lo = (s << 12) + (t << 3);
      __builtin_amdgcn_global_load_lds((g_uint*)(Ag  + ko), (lds_uint*)&As[lo],        16, 0, 0);
      __builtin_amdgcn_global_load_lds((g_uint*)(Ag2 + ko), (lds_uint*)&As[lo + 2048], 16, 0, 0);
      __builtin_amdgcn_global_load_lds((g_uint*)(Bg  + ko), (lds_uint*)&Bs[lo],        16, 0, 0);
      __builtin_amdgcn_global_load_lds((g_uint*)(Bg2 + ko), (lds_uint*)&Bs[lo + 2048], 16, 0, 0);
    }
    __syncthreads();
    #pragma unroll
    for (int s = 0; s < 2; s++){
      const int sb = s << 12;
      bf16x8 af[4], bf[4];
      #pragma unroll
      for (int mt = 0; mt < 4; mt++)
        af[mt] = *(const bf16x8*)&As[sb + ((mw + (mt << 4) + l16) << 5) + (quad << 3)];
      #pragma unroll
      for (int nt = 0; nt < 4; nt++)
        bf[nt] = *(const bf16x8*)&Bs[sb + ((nw + (nt << 4) + l16) << 5) + (quad << 3)];
      #pragma unroll
      for (int mt = 0; mt < 4; mt++)
        #pragma unroll
        for (int nt = 0; nt < 4; nt++)
          acc[mt][nt] = __builtin_amdgcn_mfma_f32_16x16x32_bf16(af[mt], bf[nt], acc[mt][nt], 0, 0, 0);
    }
    __syncthreads();
  }
  #pragma unroll
  for (int nt = 0; nt < 4; nt++){
    const int col = n0 + nw + (nt << 4) + l16;
    const float bsv = bias[col];
    #pragma unroll
    for (int mt = 0; mt < 4; mt++){
      const int row = m0 + mw + (mt << 4) + (quad << 2);
      #pragma unroll
      for (int r = 0; r < 4; r++){
        float v = acc[mt][nt][r] + bsv;
        if (RELU) v = fmaxf(v, 0.f);
        if (OUTBF) ((unsigned short*)Cout)[(size_t)(row + r) * N + col] = f2bf(v);
        else       ((float*)Cout)[(size_t)(row + r) * N + col] = v;
      }
    }
  }
}

// ---------------- bf16 MFMA GEMM, 128x64 tile, BK=64: for Wo/FFN2 (2 blocks/CU) ----------------
template<int RELU, int OUTBF>
__global__ void __launch_bounds__(256) k_gemm64n(const unsigned short* __restrict__ A,
                                                 const unsigned short* __restrict__ Bt,
                                                 const float* __restrict__ bias,
                                                 void* __restrict__ Cout, int N, int K){
  __shared__ unsigned short As[2 * 128 * 32];
  __shared__ unsigned short Bs[2 * 64 * 32];
  const int t = threadIdx.x;
  const int m0 = blockIdx.y << 7, n0 = blockIdx.x << 6;
  const int lane = t & 63, w = t >> 6;
  const int quad = lane >> 4, l16 = lane & 15;
  const int mw = (w & 1) << 6, nw = (w >> 1) << 5;
  floatx4 acc[4][2];
  #pragma unroll
  for (int i = 0; i < 4; i++)
    #pragma unroll
    for (int j = 0; j < 2; j++) acc[i][j] = (floatx4){0.f, 0.f, 0.f, 0.f};
  const unsigned short* Ag  = A  + (size_t)(m0 + (t >> 2)) * K + ((t & 3) << 3);
  const unsigned short* Ag2 = Ag + (size_t)64 * K;
  const unsigned short* Bg  = Bt + (size_t)(n0 + (t >> 2)) * K + ((t & 3) << 3);
  for (int kb = 0; kb < K; kb += 64){
    #pragma unroll
    for (int s = 0; s < 2; s++){
      const int ko = kb + (s << 5);
      __builtin_amdgcn_global_load_lds((g_uint*)(Ag  + ko), (lds_uint*)&As[(s << 12) + (t << 3)],        16, 0, 0);
      __builtin_amdgcn_global_load_lds((g_uint*)(Ag2 + ko), (lds_uint*)&As[(s << 12) + (t << 3) + 2048], 16, 0, 0);
      __builtin_amdgcn_global_load_lds((g_uint*)(Bg  + ko), (lds_uint*)&Bs[(s << 11) + (t << 3)],        16, 0, 0);
    }
    __syncthreads();
    #pragma unroll
    for (int s = 0; s < 2; s++){
      bf16x8 af[4], bf[2];
      #pragma unroll
      for (int mt = 0; mt < 4; mt++)
        af[mt] = *(const bf16x8*)&As[(s << 12) + ((mw + (mt << 4) + l16) << 5) + (quad << 3)];
      #pragma unroll
      for (int nt = 0; nt < 2; nt++)
        bf[nt] = *(const bf16x8*)&Bs[(s << 11) + ((nw + (nt << 4) + l16) << 5) + (quad << 3)];
      #pragma unroll
      for (int mt = 0; mt < 4; mt++)
        #pragma unroll
        for (int nt = 0; nt < 2; nt++)
          acc[mt][nt] = __builtin_amdgcn_mfma_f32_16x16x32_bf16(af[mt], bf[nt], acc[mt][nt], 0, 0, 0);
    }
    __syncthreads();
  }
  #pragma unroll
  for (int nt = 0; nt < 2; nt++){
    const int col = n0 + nw + (nt << 4) + l16;
    const float bsv = bias[col];
    #pragma unroll
    for (int mt = 0; mt < 4; mt++){
      const int row = m0 + mw + (mt << 4) + (quad << 2);
      #pragma unroll
      for (int r = 0; r < 4; r++){
        float v = acc[mt][nt][r] + bsv;
        if (RELU) v = fmaxf(v, 0.f);
        if (OUTBF) ((unsigned short*)Cout)[(size_t)(row + r) * N + col] = f2bf(v);
        else       ((float*)Cout)[(size_t)(row + r) * N + col] = v;
      }
    }
  }
}

// ---------------- MFMA flash attention v8: 4 waves x 32 q-rows (R=32), 128-q x 128-key tiles ----------------
// v7 was LDS-throughput-bound (~91K min LDS cy/CU + 74K conflict cy vs 194K total; MfmaUtil 16.6%).
// R=16 -> R=32: each wave owns TWO 16-q column blocks sharing the same K/V fragment reads, so the
// per-tile K and V LDS re-reads halve (each kf feeds 4 MFMAs, each vf feeds 2). 256 threads, LDS
// unchanged (69.5 KB -> 2 blocks/CU, 8 waves/CU); per-wave ILP doubles to compensate occupancy.
// s_setprio(1) around MFMA clusters (T5, attn-proven). Same-wave P round-trip kept (R13-verified).
__global__ void __launch_bounds__(256, 2) k_attn(const unsigned short* __restrict__ qkvb,
                                                 const int* __restrict__ amask,
                                                 unsigned short* __restrict__ ctxb){
  __shared__ __align__(16) unsigned short Ks[128 * AST];   // [key][d]     18.4 KB
  __shared__ __align__(16) unsigned short Vt[64 * VST];    // [d][key]     17.4 KB
  __shared__ __align__(16) unsigned short PQs[128 * VST];  // Q stage / P  34.8 KB
  __shared__ int msk[128];
  const int t = threadIdx.x;                 // 0..255
  const int w = t >> 6, lane = t & 63;       // w: 0..3
  const int quad = lane >> 4, l16 = lane & 15;
  const int b = blockIdx.y >> 4, h = blockIdx.y & 15;
  const int q0 = blockIdx.x << 7;            // 128-row q tile
  const int r0 = (w << 5) + l16;             // qc=0 row of this lane (0..127)
  const int r1 = r0 + 16;                    // qc=1 row
  const int sr = t >> 2, sc = (t & 3) << 4;  // K staging: rows sr, sr+64; 16-short chunk
  const int kg = t >> 4, dc = (t & 15) << 2; // V staging: 4-key groups kg, kg+16; 4-d chunk

  {
    const unsigned short* qs = qkvb + (size_t)((b << 11) + q0 + (t >> 1)) * 3072 + (h << 6) + ((t & 1) << 5);
    unsigned short* qd = &PQs[(t >> 1) * VST + ((t & 1) << 5)];
    *(uint4*)(qd)      = *(const uint4*)(qs);
    *(uint4*)(qd + 8)  = *(const uint4*)(qs + 8);
    *(uint4*)(qd + 16) = *(const uint4*)(qs + 16);
    *(uint4*)(qd + 24) = *(const uint4*)(qs + 24);
  }
  __syncthreads();
  const bf16x8 qa0 = *(const bf16x8*)&PQs[r0 * VST + (quad << 3)];
  const bf16x8 qa1 = *(const bf16x8*)&PQs[r0 * VST + (quad << 3) + 32];
  const bf16x8 qb0 = *(const bf16x8*)&PQs[r1 * VST + (quad << 3)];
  const bf16x8 qb1 = *(const bf16x8*)&PQs[r1 * VST + (quad << 3) + 32];

  floatx4 accA[4], accB[4];
  #pragma unroll
  for (int i = 0; i < 4; i++){
    accA[i] = (floatx4){0.f, 0.f, 0.f, 0.f};
    accB[i] = (floatx4){0.f, 0.f, 0.f, 0.f};
  }
  float l_runA = 0.f, l_runB = 0.f;

  const unsigned short* kbase  = qkvb + (size_t)((b << 11) + sr) * 3072 + 1024 + (h << 6) + sc;
  const unsigned short* kbase2 = kbase + (size_t)64 * 3072;
  const unsigned short* vbase  = qkvb + (size_t)((b << 11) + (kg << 2)) * 3072 + 2048 + (h << 6) + dc;
  const unsigned short* vbase2 = vbase + (size_t)64 * 3072;
  const int* mbase = amask + (b << 11);

  // ---- prefetch tile 0 (each thread carries 2 K rows + 8 V key-rows) ----
  uint4 krA, krB, krC, krD;
  ushort4 va0, va1, va2, va3, vb0, vb1, vb2, vb3;
  int mreg = 1;
  {
    krA = *(const uint4*)kbase;
    krB = *(const uint4*)(kbase + 8);
    krC = *(const uint4*)kbase2;
    krD = *(const uint4*)(kbase2 + 8);
    va0 = *(const ushort4*)(vbase);
    va1 = *(const ushort4*)(vbase + 3072);
    va2 = *(const ushort4*)(vbase + 2 * 3072);
    va3 = *(const ushort4*)(vbase + 3 * 3072);
    vb0 = *(const ushort4*)(vbase2);
    vb1 = *(const ushort4*)(vbase2 + 3072);
    vb2 = *(const ushort4*)(vbase2 + 2 * 3072);
    vb3 = *(const ushort4*)(vbase2 + 3 * 3072);
    if (t < 128) mreg = mbase[t];
  }

  for (int k0 = 0; k0 < SEQ; k0 += 128){
    __syncthreads();                         // A: readers done; drains prefetch loads
    *(uint4*)&Ks[sr * AST + sc]            = krA;
    *(uint4*)&Ks[sr * AST + sc + 8]        = krB;
    *(uint4*)&Ks[(sr + 64) * AST + sc]     = krC;
    *(uint4*)&Ks[(sr + 64) * AST + sc + 8] = krD;
    {
      ushort4 c;
      c.x = va0.x; c.y = va1.x; c.z = va2.x; c.w = va3.x; *(ushort4*)&Vt[(dc + 0) * VST + (kg << 2)] = c;
      c.x = va0.y; c.y = va1.y; c.z = va2.y; c.w = va3.y; *(ushort4*)&Vt[(dc + 1) * VST + (kg << 2)] = c;
      c.x = va0.z; c.y = va1.z; c.z = va2.z; c.w = va3.z; *(ushort4*)&Vt[(dc + 2) * VST + (kg << 2)] = c;
      c.x = va0.w; c.y = va1.w; c.z = va2.w; c.w = va3.w; *(ushort4*)&Vt[(dc + 3) * VST + (kg << 2)] = c;
      c.x = vb0.x; c.y = vb1.x; c.z = vb2.x; c.w = vb3.x; *(ushort4*)&Vt[(dc + 0) * VST + ((kg + 16) << 2)] = c;
      c.x = vb0.y; c.y = vb1.y; c.z = vb2.y; c.w = vb3.y; *(ushort4*)&Vt[(dc + 1) * VST + ((kg + 16) << 2)] = c;
      c.x = vb0.z; c.y = vb1.z; c.z = vb2.z; c.w = vb3.z; *(ushort4*)&Vt[(dc + 2) * VST + ((kg + 16) << 2)] = c;
      c.x = vb0.w; c.y = vb1.w; c.z = vb2.w; c.w = vb3.w; *(ushort4*)&Vt[(dc + 3) * VST + ((kg + 16) << 2)] = c;
    }
    if (t < 128) msk[t] = mreg;
    __syncthreads();                         // B: staging visible
    // ---- issue next tile's loads; drain at next iteration's barrier A ----
    if (k0 + 128 < SEQ){
      const unsigned short* ks  = kbase  + (size_t)(k0 + 128) * 3072;
      const unsigned short* ks2 = kbase2 + (size_t)(k0 + 128) * 3072;
      krA = *(const uint4*)ks;
      krB = *(const uint4*)(ks + 8);
      krC = *(const uint4*)ks2;
      krD = *(const uint4*)(ks2 + 8);
      const unsigned short* vs  = vbase  + (size_t)(k0 + 128) * 3072;
      const unsigned short* vs2 = vbase2 + (size_t)(k0 + 128) * 3072;
      va0 = *(const ushort4*)(vs);
      va1 = *(const ushort4*)(vs + 3072);
      va2 = *(const ushort4*)(vs + 2 * 3072);
      va3 = *(const ushort4*)(vs + 3 * 3072);
      vb0 = *(const ushort4*)(vs2);
      vb1 = *(const ushort4*)(vs2 + 3072);
      vb2 = *(const ushort4*)(vs2 + 2 * 3072);
      vb3 = *(const ushort4*)(vs2 + 3 * 3072);
      if (t < 128) mreg = mbase[k0 + 128 + t];
    }

    // ---- per 16-key group: S^T = K·Q^T for BOTH q-column blocks (shared kf) -> exp -> P write ----
    float lsA = 0.f, lsB = 0.f;
    #pragma unroll
    for (int mt = 0; mt < 8; mt++){
      const unsigned short* kp = &Ks[((mt << 4) + l16) * AST + (quad << 3)];
      const bf16x8 kf0 = *(const bf16x8*)(kp);
      const bf16x8 kf1 = *(const bf16x8*)(kp + 32);
      floatx4 sA = (floatx4){0.f, 0.f, 0.f, 0.f};
      floatx4 sB = (floatx4){0.f, 0.f, 0.f, 0.f};
      __builtin_amdgcn_s_setprio(1);
      sA = __builtin_amdgcn_mfma_f32_16x16x32_bf16(kf0, qa0, sA, 0, 0, 0);
      sA = __builtin_amdgcn_mfma_f32_16x16x32_bf16(kf1, qa1, sA, 0, 0, 0);
      sB = __builtin_amdgcn_mfma_f32_16x16x32_bf16(kf0, qb0, sB, 0, 0, 0);
      sB = __builtin_amdgcn_mfma_f32_16x16x32_bf16(kf1, qb1, sB, 0, 0, 0);
      __builtin_amdgcn_s_setprio(0);
      const int4 m4 = *(const int4*)&msk[(mt << 4) + (quad << 2)];
      float pA0 = m4.x ? EXP2(sA[0]) : 0.f;
      float pA1 = m4.y ? EXP2(sA[1]) : 0.f;
      float pA2 = m4.z ? EXP2(sA[2]) : 0.f;
      float pA3 = m4.w ? EXP2(sA[3]) : 0.f;
      lsA += pA0 + pA1 + pA2 + pA3;
      ushort4 oA;
      oA.x = f2bf_tr(pA0); oA.y = f2bf_tr(pA1); oA.z = f2bf_tr(pA2); oA.w = f2bf_tr(pA3);
      *(ushort4*)&PQs[r0 * VST + (mt << 4) + (quad << 2)] = oA;
      float pB0 = m4.x ? EXP2(sB[0]) : 0.f;
      float pB1 = m4.y ? EXP2(sB[1]) : 0.f;
      float pB2 = m4.z ? EXP2(sB[2]) : 0.f;
      float pB3 = m4.w ? EXP2(sB[3]) : 0.f;
      lsB += pB0 + pB1 + pB2 + pB3;
      ushort4 oB;
      oB.x = f2bf_tr(pB0); oB.y = f2bf_tr(pB1); oB.z = f2bf_tr(pB2); oB.w = f2bf_tr(pB3);
      *(ushort4*)&PQs[r1 * VST + (mt << 4) + (quad << 2)] = oB;
    }
    lsA += __shfl_xor(lsA, 16);
    lsA += __shfl_xor(lsA, 32);
    l_runA += lsA;
    lsB += __shfl_xor(lsB, 16);
    lsB += __shfl_xor(lsB, 32);
    l_runB += lsB;
    asm volatile("" ::: "memory");           // forbid reordering P reads before the writes
    // ---- O^T[d][q] += V^T[d][k]·P^T[k][q]; vf shared across both q-column blocks ----
    bf16x8 pA[4], pB[4];
    #pragma unroll
    for (int s = 0; s < 4; s++){
      pA[s] = *(const bf16x8*)&PQs[r0 * VST + (s << 5) + (quad << 3)];
      pB[s] = *(const bf16x8*)&PQs[r1 * VST + (s << 5) + (quad << 3)];
    }
    #pragma unroll
    for (int mt = 0; mt < 4; mt++){
      const unsigned short* vp = &Vt[((mt << 4) + l16) * VST + (quad << 3)];
      __builtin_amdgcn_s_setprio(1);
      #pragma unroll
      for (int s = 0; s < 4; s++){
        const bf16x8 vf = *(const bf16x8*)(vp + (s << 5));
        accA[mt] = __builtin_amdgcn_mfma_f32_16x16x32_bf16(vf, pA[s], accA[mt], 0, 0, 0);
        accB[mt] = __builtin_amdgcn_mfma_f32_16x16x32_bf16(vf, pB[s], accB[mt], 0, 0, 0);
      }
      __builtin_amdgcn_s_setprio(0);
    }
  }
  // ---- epilogue: O[q][d] = accO / l_run for both q rows ----
  const float liA = 1.f / l_runA;
  const float liB = 1.f / l_runB;
  unsigned short* oA = ctxb + (size_t)((b << 11) + q0 + r0) * 1024 + (h << 6);
  unsigned short* oB = ctxb + (size_t)((b << 11) + q0 + r1) * 1024 + (h << 6);
  #pragma unroll
  for (int mt = 0; mt < 4; mt++){
    ushort4 o;
    o.x = f2bf(accA[mt][0] * liA);
    o.y = f2bf(accA[mt][1] * liA);
    o.z = f2bf(accA[mt][2] * liA);
    o.w = f2bf(accA[mt][3] * liA);
    *(ushort4*)&oA[(mt << 4) + (quad << 2)] = o;
    o.x = f2bf(accB[mt][0] * liB);
    o.y = f2bf(accB[mt][1] * liB);
    o.z = f2bf(accB[mt][2] * liB);
    o.w = f2bf(accB[mt][3] * liB);
    *(ushort4*)&oB[(mt << 4) + (quad << 2)] = o;
  }
}

// ---------------- residual + LayerNorm (1024 cols, one block per row); a is bf16 ----------------
__global__ void __launch_bounds__(256) k_ln(const unsigned short* __restrict__ a,
                                            const float* __restrict__ res,
                                            const float* __restrict__ gg, const float* __restrict__ bb,
                                            float* __restrict__ out, unsigned short* __restrict__ outb){
  const int row = blockIdx.x, t = threadIdx.x;
  const ushort4 au = ((const ushort4*)(a + (size_t)row * 1024))[t];
  const float4 rv = ((const float4*)(res + (size_t)row * 1024))[t];
  float4 v;
  { union { unsigned u; float f; } c;
    c.u = (unsigned)au.x << 16; v.x = c.f + rv.x;
    c.u = (unsigned)au.y << 16; v.y = c.f + rv.y;
    c.u = (unsigned)au.z << 16; v.z = c.f + rv.z;
    c.u = (unsigned)au.w << 16; v.w = c.f + rv.w; }
  float sum = v.x + v.y + v.z + v.w;
  float ss  = v.x * v.x + v.y * v.y + v.z * v.z + v.w * v.w;
  #pragma unroll
  for (int off = 32; off > 0; off >>= 1){
    sum += __shfl_down(sum, off);
    ss  += __shfl_down(ss, off);
  }
  __shared__ float red[8];
  const int w = t >> 6;
  if ((t & 63) == 0){ red[w] = sum; red[4 + w] = ss; }
  __syncthreads();
  const float S  = red[0] + red[1] + red[2] + red[3];
  const float SS = red[4] + red[5] + red[6] + red[7];
  const float mu  = S * (1.f / 1024.f);
  const float var = SS * (1.f / 1024.f) - mu * mu;
  const float rs  = rsqrtf(var + 1e-5f);
  const float4 gv = ((const float4*)gg)[t];
  const float4 bv = ((const float4*)bb)[t];
  float4 o;
  o.x = (v.x - mu) * rs * gv.x + bv.x;
  o.y = (v.y - mu) * rs * gv.y + bv.y;
  o.z = (v.z - mu) * rs * gv.z + bv.z;
  o.w = (v.w - mu) * rs * gv.w + bv.w;
  ((float4*)(out + (size_t)row * 1024))[t] = o;
  if (outb){
    ushort4 ob; ob.x = f2bf(o.x); ob.y = f2bf(o.y); ob.z = f2bf(o.z); ob.w = f2bf(o.w);
    ((ushort4*)(outb + (size_t)row * 1024))[t] = ob;
  }
}

extern "C" void kernel_launch(void* const* d_in, const int* in_sizes, int n_in,
                              void* d_out, int out_size, void* d_ws, size_t ws_size,
                              hipStream_t stream){
  const float* x     = (const float*)d_in[0];
  const int*   amask = (const int*)d_in[1];
  const float* Wq    = (const float*)d_in[2];
  const float* bq    = (const float*)d_in[3];
  const float* Wk    = (const float*)d_in[4];
  const float* bk    = (const float*)d_in[5];
  const float* Wv    = (const float*)d_in[6];
  const float* bv    = (const float*)d_in[7];
  const float* Wo    = (const float*)d_in[8];
  const float* bo    = (const float*)d_in[9];
  const float* g1    = (const float*)d_in[10];
  const float* b1    = (const float*)d_in[11];
  const float* W1    = (const float*)d_in[12];
  const float* bias1 = (const float*)d_in[13];
  const float* W2    = (const float*)d_in[14];
  const float* bias2 = (const float*)d_in[15];
  const float* g2    = (const float*)d_in[16];
  const float* b2    = (const float*)d_in[17];

  char* ws = (char*)d_ws;
  unsigned short* xb    = (unsigned short*)(ws + 0);            //  8 MB
  unsigned short* wqkvt = (unsigned short*)(ws + 8388608);      //  6 MB
  float*          qbias = (float*)         (ws + 14680064);     // 12 KB
  unsigned short* wot   = (unsigned short*)(ws + 14692352);     //  2 MB
  unsigned short* w1t   = (unsigned short*)(ws + 16789504);     //  4 MB
  unsigned short* w2t   = (unsigned short*)(ws + 20983808);     //  4 MB
  unsigned short* ctxb  = (unsigned short*)(ws + 25178112);     //  8 MB
  unsigned short* attnb = (unsigned short*)(ws + 33566720);     //  8 MB bf16 (Wo out; later FFN2 out)
  unsigned short* fbufb = attnb;
  unsigned short* qkvb  = (unsigned short*)(ws + 50343936);     // 24 MB: QKV bf16 [4096][3072]
  float*          out1  = (float*)         (ws + 50343936);     // 16 MB fp32, reuse (qkvb dead after attn)
  unsigned short* out1b = (unsigned short*)(ws + 50343936 + 25165824);  // 8 MB
  unsigned short* h1    = (unsigned short*)(ws + 50343936 + 33554432);  // 16 MB

  // --- prep (2 kernels) ---
  k_cvt_qb<<<dim3(4108), dim3(256), 0, stream>>>(x, xb, bq, bk, bv, qbias);
  k_prep_w<<<dim3(8192), dim3(256), 0, stream>>>(Wo, W1, W2, Wq, Wk, Wv, wot, w1t, w2t, wqkvt);

  // --- QKV projection -> bf16 (Q pre-scaled by 0.125*log2e via Wq/bq): 768 blocks = 3/CU ---
  k_gemm128<0,1><<<dim3(24, 32), dim3(256), 0, stream>>>(xb, wqkvt, qbias, qkvb, 3072, 1024);
  // --- MFMA flash attention v8: 4 waves x 32 q-rows, 128-q x 128-key tiles -> ctxb bf16 ---
  k_attn<<<dim3(16, 32), dim3(256), 0, stream>>>(qkvb, amask, ctxb);
  // --- output projection: 128x64 tile -> 512 blocks = 2/CU, bf16 out ---
  k_gemm64n<0,1><<<dim3(16, 32), dim3(256), 0, stream>>>(ctxb, wot, bo, attnb, MDIM, 1024);
  // --- LN1(attnb + x) -> out1 fp32 + out1b bf16 ---
  k_ln<<<dim3(4096), dim3(256), 0, stream>>>(attnb, x, g1, b1, out1, out1b);
  // --- FFN ---
  k_gemm128<1,1><<<dim3(16, 32), dim3(256), 0, stream>>>(out1b, w1t, bias1, h1, FFH, 1024);
  k_gemm64n<0,1><<<dim3(16, 32), dim3(256), 0, stream>>>(h1, w2t, bias2, fbufb, MDIM, 2048);
  // --- LN2(fbufb + out1) -> d_out ---
  k_ln<<<dim3(4096), dim3(256), 0, stream>>>(fbufb, out1, g2, b2, (float*)d_out, nullptr);
}

// Round 2
// 312.564 us; speedup vs baseline: 1.0795x; 1.0487x over previous
//
#include <hip/hip_runtime.h>

#define MDIM 1024
#define FFH  2048
#define SEQ  2048
#define AST  72    // Ks row stride (shorts): 144 B, 16B multiple (16B alignment mandatory: R6/R7)
#define VST  136   // Vt row stride (128 keys + 8 pad): 272 B, 16B multiple
#define QSCL 0.18033688f   // 0.125 * log2(e): scores exit MFMA in log2 domain -> raw v_exp_f32

// exp2f libcall carries a denormal-fixup sequence (R10: attn VALUBusy 46.8->55.6, +9us).
#if __has_builtin(__builtin_amdgcn_exp2f)
  #define EXP2(x) __builtin_amdgcn_exp2f(x)
#else
  #define EXP2(x) exp2f(x)
#endif

typedef __attribute__((ext_vector_type(8))) __bf16 bf16x8;
typedef __attribute__((ext_vector_type(4))) float floatx4;
typedef __attribute__((ext_vector_type(8))) unsigned short ushort8;
typedef __attribute__((address_space(3))) unsigned int lds_uint;
typedef const __attribute__((address_space(1))) unsigned int g_uint;

__device__ __forceinline__ unsigned short f2bf(float f){
  union { float f; unsigned u; } v; v.f = f;
  unsigned u = v.u;
  u += 0x7fffu + ((u >> 16) & 1u);
  return (unsigned short)(u >> 16);
}
__device__ __forceinline__ unsigned short f2bf_tr(float f){   // truncating (P >= 0, softmax-internal)
  union { float f; unsigned u; } v; v.f = f;
  return (unsigned short)(v.u >> 16);
}

// ---------------- prep kernel 1: x -> bf16 (blocks 0..4095) + qbias build (blocks 4096..4107) ----------------
__global__ void k_cvt_qb(const float* __restrict__ x, unsigned short* __restrict__ xb,
                         const float* __restrict__ bq, const float* __restrict__ bk,
                         const float* __restrict__ bv, float* __restrict__ qbias){
  const int bid = blockIdx.x, t = threadIdx.x;
  if (bid < 4096){
    int i = (bid * 256 + t) * 4;
    float4 v = *(const float4*)(x + i);
    ushort4 o;
    o.x = f2bf(v.x); o.y = f2bf(v.y); o.z = f2bf(v.z); o.w = f2bf(v.w);
    *(ushort4*)(xb + i) = o;
  } else {
    int i = (bid - 4096) * 256 + t;   // 0..3071
    qbias[i] = (i < 1024) ? bq[i] * QSCL : (i < 2048) ? bk[i - 1024] : bv[i - 2048];
  }
}

// ---------------- prep kernel 2: all weight transposes (block-uniform branches) ----------------
// bid <1024: Wo[1024][1024]->wot | <3072: W1[1024][2048]->w1t | <5120: W2[2048][1024]->w2t
// | <8192: Wq/Wk/Wv [16][1024][64] -> fused wqkvt [3072][1024] (Wq pre-scaled QSCL)
__global__ void __launch_bounds__(256) k_prep_w(const float* __restrict__ Wo, const float* __restrict__ W1,
                                                const float* __restrict__ W2, const float* __restrict__ Wq,
                                                const float* __restrict__ Wk, const float* __restrict__ Wv,
                                                unsigned short* __restrict__ wot, unsigned short* __restrict__ w1t,
                                                unsigned short* __restrict__ w2t, unsigned short* __restrict__ wqkvt){
  __shared__ unsigned short Ts[32 * 36];
  const int t = threadIdx.x, bid = blockIdx.x;
  const int lr = t >> 3, lc4 = (t & 7) << 2;
  if (bid >= 5120){
    const int id = bid - 5120;                  // [0,3072)
    const int xm = id & 31, yd = (id >> 5) & 1, z = id >> 6;   // z in [0,48)
    const int tensor = z >> 4, h = z & 15;
    const float* W = (tensor == 0) ? Wq : (tensor == 1) ? Wk : Wv;
    const float scl = (tensor == 0) ? QSCL : 1.0f;
    const int m0 = xm << 5, d0 = yd << 5;
    float4 v = *(const float4*)(W + ((size_t)h << 16) + (size_t)(m0 + lr) * 64 + d0 + lc4);
    ushort4 o; o.x = f2bf(v.x * scl); o.y = f2bf(v.y * scl); o.z = f2bf(v.z * scl); o.w = f2bf(v.w * scl);
    *(ushort4*)&Ts[lr * 36 + lc4] = o;
    __syncthreads();
    ushort4 w;
    w.x = Ts[(lc4 + 0) * 36 + lr];
    w.y = Ts[(lc4 + 1) * 36 + lr];
    w.z = Ts[(lc4 + 2) * 36 + lr];
    w.w = Ts[(lc4 + 3) * 36 + lr];
    const int n = (tensor << 10) + (h << 6) + d0 + lr;
    *(ushort4*)(wqkvt + ((size_t)n << 10) + m0 + lc4) = w;
    return;
  }
  const float* src; unsigned short* dst; int K, N, k0, n0;
  if (bid < 1024){
    src = Wo; dst = wot; K = 1024; N = 1024;
    n0 = (bid & 31) << 5; k0 = (bid >> 5) << 5;
  } else if (bid < 3072){
    const int id = bid - 1024;
    src = W1; dst = w1t; K = 1024; N = 2048;
    n0 = (id & 63) << 5; k0 = (id >> 6) << 5;
  } else {
    const int id = bid - 3072;
    src = W2; dst = w2t; K = 2048; N = 1024;
    n0 = (id & 31) << 5; k0 = (id >> 5) << 5;
  }
  float4 v = *(const float4*)(src + (size_t)(k0 + lr) * N + n0 + lc4);
  ushort4 o; o.x = f2bf(v.x); o.y = f2bf(v.y); o.z = f2bf(v.z); o.w = f2bf(v.w);
  *(ushort4*)&Ts[lr * 36 + lc4] = o;
  __syncthreads();
  ushort4 w;
  w.x = Ts[(lc4 + 0) * 36 + lr];
  w.y = Ts[(lc4 + 1) * 36 + lr];
  w.z = Ts[(lc4 + 2) * 36 + lr];
  w.w = Ts[(lc4 + 3) * 36 + lr];
  *(ushort4*)(dst + (size_t)(n0 + lr) * K + k0 + lc4) = w;
}

// ---------------- bf16 MFMA GEMM, 128x128 tile, BK=64 (two [128][32] sub-buffers) ----------------
template<int RELU, int OUTBF>
__global__ void __launch_bounds__(256) k_gemm128(const unsigned short* __restrict__ A,
                                                 const unsigned short* __restrict__ Bt,
                                                 const float* __restrict__ bias,
                                                 void* __restrict__ Cout, int N, int K){
  __shared__ unsigned short As[2 * 128 * 32];
  __shared__ unsigned short Bs[2 * 128 * 32];
  const int t = threadIdx.x;
  const int m0 = blockIdx.y << 7, n0 = blockIdx.x << 7;
  const int lane = t & 63, w = t >> 6;
  const int quad = lane >> 4, l16 = lane & 15;
  const int mw = (w & 1) << 6, nw = (w >> 1) << 6;
  floatx4 acc[4][4];
  #pragma unroll
  for (int i = 0; i < 4; i++)
    #pragma unroll
    for (int j = 0; j < 4; j++) acc[i][j] = (floatx4){0.f, 0.f, 0.f, 0.f};
  const unsigned short* Ag  = A  + (size_t)(m0 + (t >> 2)) * K + ((t & 3) << 3);
  const unsigned short* Ag2 = Ag + (size_t)64 * K;
  const unsigned short* Bg  = Bt + (size_t)(n0 + (t >> 2)) * K + ((t & 3) << 3);
  const unsigned short* Bg2 = Bg + (size_t)64 * K;
  for (int kb = 0; kb < K; kb += 64){
    #pragma unroll
    for (int s = 0; s < 2; s++){
      const int ko = kb + (s << 5), lo = (s << 12) + (t << 3);
      __builtin_amdgcn_global_load_lds((g_uint*)(Ag  + ko), (lds_uint*)&As[lo],        16, 0, 0);
      __builtin_amdgcn_global_load_lds((g_uint*)(Ag2 + ko), (lds_uint*)&As[lo + 2048], 16, 0, 0);
      __builtin_amdgcn_global_load_lds((g_uint*)(Bg  + ko), (lds_uint*)&Bs[lo],        16, 0, 0);
      __builtin_amdgcn_global_load_lds((g_uint*)(Bg2 + ko), (lds_uint*)&Bs[lo + 2048], 16, 0, 0);
    }
    __syncthreads();
    #pragma unroll
    for (int s = 0; s < 2; s++){
      const int sb = s << 12;
      bf16x8 af[4], bf[4];
      #pragma unroll
      for (int mt = 0; mt < 4; mt++)
        af[mt] = *(const bf16x8*)&As[sb + ((mw + (mt << 4) + l16) << 5) + (quad << 3)];
      #pragma unroll
      for (int nt = 0; nt < 4; nt++)
        bf[nt] = *(const bf16x8*)&Bs[sb + ((nw + (nt << 4) + l16) << 5) + (quad << 3)];
      #pragma unroll
      for (int mt = 0; mt < 4; mt++)
        #pragma unroll
        for (int nt = 0; nt < 4; nt++)
          acc[mt][nt] = __builtin_amdgcn_mfma_f32_16x16x32_bf16(af[mt], bf[nt], acc[mt][nt], 0, 0, 0);
    }
    __syncthreads();
  }
  #pragma unroll
  for (int nt = 0; nt < 4; nt++){
    const int col = n0 + nw + (nt << 4) + l16;
    const float bsv = bias[col];
    #pragma unroll
    for (int mt = 0; mt < 4; mt++){
      const int row = m0 + mw + (mt << 4) + (quad << 2);
      #pragma unroll
      for (int r = 0; r < 4; r++){
        float v = acc[mt][nt][r] + bsv;
        if (RELU) v = fmaxf(v, 0.f);
        if (OUTBF) ((unsigned short*)Cout)[(size_t)(row + r) * N + col] = f2bf(v);
        else       ((float*)Cout)[(size_t)(row + r) * N + col] = v;
      }
    }
  }
}

// ---------------- bf16 MFMA GEMM, 128x64 tile, BK=64: for Wo/FFN2 (2 blocks/CU) ----------------
template<int RELU, int OUTBF>
__global__ void __launch_bounds__(256) k_gemm64n(const unsigned short* __restrict__ A,
                                                 const unsigned short* __restrict__ Bt,
                                                 const float* __restrict__ bias,
                                                 void* __restrict__ Cout, int N, int K){
  __shared__ unsigned short As[2 * 128 * 32];
  __shared__ unsigned short Bs[2 * 64 * 32];
  const int t = threadIdx.x;
  const int m0 = blockIdx.y << 7, n0 = blockIdx.x << 6;
  const int lane = t & 63, w = t >> 6;
  const int quad = lane >> 4, l16 = lane & 15;
  const int mw = (w & 1) << 6, nw = (w >> 1) << 5;
  floatx4 acc[4][2];
  #pragma unroll
  for (int i = 0; i < 4; i++)
    #pragma unroll
    for (int j = 0; j < 2; j++) acc[i][j] = (floatx4){0.f, 0.f, 0.f, 0.f};
  const unsigned short* Ag  = A  + (size_t)(m0 + (t >> 2)) * K + ((t & 3) << 3);
  const unsigned short* Ag2 = Ag + (size_t)64 * K;
  const unsigned short* Bg  = Bt + (size_t)(n0 + (t >> 2)) * K + ((t & 3) << 3);
  for (int kb = 0; kb < K; kb += 64){
    #pragma unroll
    for (int s = 0; s < 2; s++){
      const int ko = kb + (s << 5);
      __builtin_amdgcn_global_load_lds((g_uint*)(Ag  + ko), (lds_uint*)&As[(s << 12) + (t << 3)],        16, 0, 0);
      __builtin_amdgcn_global_load_lds((g_uint*)(Ag2 + ko), (lds_uint*)&As[(s << 12) + (t << 3) + 2048], 16, 0, 0);
      __builtin_amdgcn_global_load_lds((g_uint*)(Bg  + ko), (lds_uint*)&Bs[(s << 11) + (t << 3)],        16, 0, 0);
    }
    __syncthreads();
    #pragma unroll
    for (int s = 0; s < 2; s++){
      bf16x8 af[4], bf[2];
      #pragma unroll
      for (int mt = 0; mt < 4; mt++)
        af[mt] = *(const bf16x8*)&As[(s << 12) + ((mw + (mt << 4) + l16) << 5) + (quad << 3)];
      #pragma unroll
      for (int nt = 0; nt < 2; nt++)
        bf[nt] = *(const bf16x8*)&Bs[(s << 11) + ((nw + (nt << 4) + l16) << 5) + (quad << 3)];
      #pragma unroll
      for (int mt = 0; mt < 4; mt++)
        #pragma unroll
        for (int nt = 0; nt < 2; nt++)
          acc[mt][nt] = __builtin_amdgcn_mfma_f32_16x16x32_bf16(af[mt], bf[nt], acc[mt][nt], 0, 0, 0);
    }
    __syncthreads();
  }
  #pragma unroll
  for (int nt = 0; nt < 2; nt++){
    const int col = n0 + nw + (nt << 4) + l16;
    const float bsv = bias[col];
    #pragma unroll
    for (int mt = 0; mt < 4; mt++){
      const int row = m0 + mw + (mt << 4) + (quad << 2);
      #pragma unroll
      for (int r = 0; r < 4; r++){
        float v = acc[mt][nt][r] + bsv;
        if (RELU) v = fmaxf(v, 0.f);
        if (OUTBF) ((unsigned short*)Cout)[(size_t)(row + r) * N + col] = f2bf(v);
        else       ((float*)Cout)[(size_t)(row + r) * N + col] = v;
      }
    }
  }
}

// ---------------- MFMA flash attention v9: in-register P (sigma-permuted V cols) + K/V dbuf ----------------
// v8 post-mortem: LDS-bound incl. ~450 conflict cy/wave-tile (V transpose-writes 8-way) + P LDS
// round-trip (24 ops + serial chain). v9:
//  (a) P never touches LDS: key-permutation sigma(32s+8q+j) = 32s+16*(j>>2)+4q+(j&3) applied to
//      Vt COLUMNS makes the PV B-fragment exactly lane-local (QK output regs j of groups 2s,2s+1).
//  (b) Vt block-XOR swizzle: 16B-block' = block ^ ((d_row>>4)&3). Write-side spreads banks
//      (2-way, free); read-side XOR is constant per instruction (mt) -> balance unchanged.
//  (c) K/V double-buffered (PQs freed) -> ONE barrier per tile: write t+1 into buf^1 while
//      computing buf c; end-of-tile barrier gives visibility + WAR protection.
//  (d) l_run cross-quad shuffles deferred to epilogue (no running max -> sum is linear).
__global__ void __launch_bounds__(256, 2) k_attn(const unsigned short* __restrict__ qkvb,
                                                 const int* __restrict__ amask,
                                                 unsigned short* __restrict__ ctxb){
  __shared__ __align__(16) unsigned short Ks[2][128 * AST];   // [key][d]  2x 18.4 KB
  __shared__ __align__(16) unsigned short Vt[2][64 * VST];    // [d][key'] 2x 17.4 KB
  __shared__ __align__(16) int msk[2][128];
  const int t = threadIdx.x;                 // 0..255
  const int w = t >> 6, lane = t & 63;       // w: 0..3
  const int quad = lane >> 4, l16 = lane & 15;
  const int b = blockIdx.y >> 4, h = blockIdx.y & 15;
  const int q0 = blockIdx.x << 7;            // 128-row q tile
  const int r0 = (w << 5) + l16;             // qc=0 row of this lane (0..127)
  const int r1 = r0 + 16;                    // qc=1 row
  const int sr = t >> 2, sc = (t & 3) << 4;  // K staging: rows sr, sr+64; 16-short chunk
  const int kg = t >> 4, dc = (t & 15) << 2; // V staging: 4-key groups kg, kg+16; 4-d chunk
  // sigma + bank-swizzle constants for V staging (keys 4kg+i -> phys col pc0+i; +64 for kg+16)
  const int swz  = (dc >> 4) & 3;                        // = (row>>4)&3, constant per thread
  const int pc0  = ((((kg & 3) | ((kg >> 3) << 2)) ^ swz) << 3) | (((kg >> 2) & 1) << 2);

  // ---- Q stage via Ks[0] (one-time) ----
  {
    const int qr = t >> 1, qc = (t & 1) << 5;
    const unsigned short* qs = qkvb + (size_t)((b << 11) + q0 + qr) * 3072 + (h << 6) + qc;
    unsigned short* qd = &Ks[0][qr * AST + qc];
    *(uint4*)(qd)      = *(const uint4*)(qs);
    *(uint4*)(qd + 8)  = *(const uint4*)(qs + 8);
    *(uint4*)(qd + 16) = *(const uint4*)(qs + 16);
    *(uint4*)(qd + 24) = *(const uint4*)(qs + 24);
  }
  __syncthreads();
  const bf16x8 qa0 = *(const bf16x8*)&Ks[0][r0 * AST + (quad << 3)];
  const bf16x8 qa1 = *(const bf16x8*)&Ks[0][r0 * AST + (quad << 3) + 32];
  const bf16x8 qb0 = *(const bf16x8*)&Ks[0][r1 * AST + (quad << 3)];
  const bf16x8 qb1 = *(const bf16x8*)&Ks[0][r1 * AST + (quad << 3) + 32];

  floatx4 accA[4], accB[4];
  #pragma unroll
  for (int i = 0; i < 4; i++){
    accA[i] = (floatx4){0.f, 0.f, 0.f, 0.f};
    accB[i] = (floatx4){0.f, 0.f, 0.f, 0.f};
  }
  float l_runA = 0.f, l_runB = 0.f;

  const unsigned short* kbase  = qkvb + (size_t)((b << 11) + sr) * 3072 + 1024 + (h << 6) + sc;
  const unsigned short* kbase2 = kbase + (size_t)64 * 3072;
  const unsigned short* vbase  = qkvb + (size_t)((b << 11) + (kg << 2)) * 3072 + 2048 + (h << 6) + dc;
  const unsigned short* vbase2 = vbase + (size_t)64 * 3072;
  const int* mbase = amask + (b << 11);

  uint4 krA, krB, krC, krD;
  ushort4 va0, va1, va2, va3, vb0, vb1, vb2, vb3;
  int mreg = 1;

#define LOADT(tt) { \
    const size_t off = (size_t)((tt) << 7) * 3072; \
    krA = *(const uint4*)(kbase + off); \
    krB = *(const uint4*)(kbase + off + 8); \
    krC = *(const uint4*)(kbase2 + off); \
    krD = *(const uint4*)(kbase2 + off + 8); \
    va0 = *(const ushort4*)(vbase + off); \
    va1 = *(const ushort4*)(vbase + off + 3072); \
    va2 = *(const ushort4*)(vbase + off + 2 * 3072); \
    va3 = *(const ushort4*)(vbase + off + 3 * 3072); \
    vb0 = *(const ushort4*)(vbase2 + off); \
    vb1 = *(const ushort4*)(vbase2 + off + 3072); \
    vb2 = *(const ushort4*)(vbase2 + off + 2 * 3072); \
    vb3 = *(const ushort4*)(vbase2 + off + 3 * 3072); \
    if (t < 128) mreg = mbase[((tt) << 7) + t]; \
  }

#define STORET(dst) { \
    unsigned short* Kd = Ks[dst]; \
    unsigned short* Vd = Vt[dst]; \
    *(uint4*)&Kd[sr * AST + sc]            = krA; \
    *(uint4*)&Kd[sr * AST + sc + 8]        = krB; \
    *(uint4*)&Kd[(sr + 64) * AST + sc]     = krC; \
    *(uint4*)&Kd[(sr + 64) * AST + sc + 8] = krD; \
    ushort4 cc; \
    cc.x = va0.x; cc.y = va1.x; cc.z = va2.x; cc.w = va3.x; *(ushort4*)&Vd[(dc + 0) * VST + pc0] = cc; \
    cc.x = va0.y; cc.y = va1.y; cc.z = va2.y; cc.w = va3.y; *(ushort4*)&Vd[(dc + 1) * VST + pc0] = cc; \
    cc.x = va0.z; cc.y = va1.z; cc.z = va2.z; cc.w = va3.z; *(ushort4*)&Vd[(dc + 2) * VST + pc0] = cc; \
    cc.x = va0.w; cc.y = va1.w; cc.z = va2.w; cc.w = va3.w; *(ushort4*)&Vd[(dc + 3) * VST + pc0] = cc; \
    cc.x = vb0.x; cc.y = vb1.x; cc.z = vb2.x; cc.w = vb3.x; *(ushort4*)&Vd[(dc + 0) * VST + pc0 + 64] = cc; \
    cc.x = vb0.y; cc.y = vb1.y; cc.z = vb2.y; cc.w = vb3.y; *(ushort4*)&Vd[(dc + 1) * VST + pc0 + 64] = cc; \
    cc.x = vb0.z; cc.y = vb1.z; cc.z = vb2.z; cc.w = vb3.z; *(ushort4*)&Vd[(dc + 2) * VST + pc0 + 64] = cc; \
    cc.x = vb0.w; cc.y = vb1.w; cc.z = vb2.w; cc.w = vb3.w; *(ushort4*)&Vd[(dc + 3) * VST + pc0 + 64] = cc; \
    if (t < 128) msk[dst][t] = mreg; \
  }

  // ---- prologue: tile0 -> buf0; issue tile1 prefetch ----
  LOADT(0);
  __syncthreads();            // Q fragment reads complete before Ks[0] overwrite
  STORET(0);
  LOADT(1);
  __syncthreads();            // buf0 staging visible

  int c = 0;
  for (int kt = 0; kt < 16; kt++){
    if (kt + 1 < 16) STORET(c ^ 1);       // write prefetched tile kt+1 into other buffer
    if (kt + 2 < 16) LOADT(kt + 2);       // issue global loads for tile kt+2
    {
      const unsigned short* Kc = Ks[c];
      const unsigned short* Vc = Vt[c];
      const int* Mc = msk[c];
      float lsA = 0.f, lsB = 0.f;
      #pragma unroll
      for (int s = 0; s < 4; s++){
        // ---- QK^T for key groups g0=2s (rows 32s..), g1=2s+1 (rows 32s+16..) ----
        const unsigned short* kp = &Kc[((s << 5) + l16) * AST + (quad << 3)];
        const bf16x8 k00 = *(const bf16x8*)(kp);
        const bf16x8 k01 = *(const bf16x8*)(kp + 32);
        const bf16x8 k10 = *(const bf16x8*)(kp + (AST << 4));
        const bf16x8 k11 = *(const bf16x8*)(kp + (AST << 4) + 32);
        floatx4 sA0 = (floatx4){0.f, 0.f, 0.f, 0.f};
        floatx4 sB0 = (floatx4){0.f, 0.f, 0.f, 0.f};
        floatx4 sA1 = (floatx4){0.f, 0.f, 0.f, 0.f};
        floatx4 sB1 = (floatx4){0.f, 0.f, 0.f, 0.f};
        __builtin_amdgcn_s_setprio(1);
        sA0 = __builtin_amdgcn_mfma_f32_16x16x32_bf16(k00, qa0, sA0, 0, 0, 0);
        sA0 = __builtin_amdgcn_mfma_f32_16x16x32_bf16(k01, qa1, sA0, 0, 0, 0);
        sB0 = __builtin_amdgcn_mfma_f32_16x16x32_bf16(k00, qb0, sB0, 0, 0, 0);
        sB0 = __builtin_amdgcn_mfma_f32_16x16x32_bf16(k01, qb1, sB0, 0, 0, 0);
        sA1 = __builtin_amdgcn_mfma_f32_16x16x32_bf16(k10, qa0, sA1, 0, 0, 0);
        sA1 = __builtin_amdgcn_mfma_f32_16x16x32_bf16(k11, qa1, sA1, 0, 0, 0);
        sB1 = __builtin_amdgcn_mfma_f32_16x16x32_bf16(k10, qb0, sB1, 0, 0, 0);
        sB1 = __builtin_amdgcn_mfma_f32_16x16x32_bf16(k11, qb1, sB1, 0, 0, 0);
        __builtin_amdgcn_s_setprio(0);
        // ---- masked exp (log2 domain) ----
        const int4 m0 = *(const int4*)&Mc[(s << 5) + (quad << 2)];
        const int4 m1 = *(const int4*)&Mc[(s << 5) + 16 + (quad << 2)];
        const float a0 = m0.x ? EXP2(sA0[0]) : 0.f;
        const float a1 = m0.y ? EXP2(sA0[1]) : 0.f;
        const float a2 = m0.z ? EXP2(sA0[2]) : 0.f;
        const float a3 = m0.w ? EXP2(sA0[3]) : 0.f;
        const float a4 = m1.x ? EXP2(sA1[0]) : 0.f;
        const float a5 = m1.y ? EXP2(sA1[1]) : 0.f;
        const float a6 = m1.z ? EXP2(sA1[2]) : 0.f;
        const float a7 = m1.w ? EXP2(sA1[3]) : 0.f;
        const float b0 = m0.x ? EXP2(sB0[0]) : 0.f;
        const float b1 = m0.y ? EXP2(sB0[1]) : 0.f;
        const float b2 = m0.z ? EXP2(sB0[2]) : 0.f;
        const float b3 = m0.w ? EXP2(sB0[3]) : 0.f;
        const float b4 = m1.x ? EXP2(sB1[0]) : 0.f;
        const float b5 = m1.y ? EXP2(sB1[1]) : 0.f;
        const float b6 = m1.z ? EXP2(sB1[2]) : 0.f;
        const float b7 = m1.w ? EXP2(sB1[3]) : 0.f;
        lsA += (a0 + a1) + (a2 + a3) + (a4 + a5) + (a6 + a7);
        lsB += (b0 + b1) + (b2 + b3) + (b4 + b5) + (b6 + b7);
        // ---- pack P fragments, lane-local by sigma: slots 0-3 <- g0 regs, 4-7 <- g1 regs ----
        ushort8 uA, uB;
        uA[0] = f2bf_tr(a0); uA[1] = f2bf_tr(a1); uA[2] = f2bf_tr(a2); uA[3] = f2bf_tr(a3);
        uA[4] = f2bf_tr(a4); uA[5] = f2bf_tr(a5); uA[6] = f2bf_tr(a6); uA[7] = f2bf_tr(a7);
        uB[0] = f2bf_tr(b0); uB[1] = f2bf_tr(b1); uB[2] = f2bf_tr(b2); uB[3] = f2bf_tr(b3);
        uB[4] = f2bf_tr(b4); uB[5] = f2bf_tr(b5); uB[6] = f2bf_tr(b6); uB[7] = f2bf_tr(b7);
        const bf16x8 pfA = __builtin_bit_cast(bf16x8, uA);
        const bf16x8 pfB = __builtin_bit_cast(bf16x8, uB);
        // ---- PV: O^T[d][q] += V^T[d][sigma(k)]*P^T[sigma(k)][q] ----
        __builtin_amdgcn_s_setprio(1);
        #pragma unroll
        for (int mt = 0; mt < 4; mt++){
          const bf16x8 vf = *(const bf16x8*)&Vc[((mt << 4) + l16) * VST + ((((s << 2) + quad) ^ mt) << 3)];
          accA[mt] = __builtin_amdgcn_mfma_f32_16x16x32_bf16(vf, pfA, accA[mt], 0, 0, 0);
          accB[mt] = __builtin_amdgcn_mfma_f32_16x16x32_bf16(vf, pfB, accB[mt], 0, 0, 0);
        }
        __builtin_amdgcn_s_setprio(0);
      }
      l_runA += lsA;
      l_runB += lsB;
    }
    __syncthreads();           // buf c readers done + buf c^1 staging visible
    c ^= 1;
  }
#undef LOADT
#undef STORET

  // ---- epilogue: deferred cross-quad l reduction, then O[q][d] = accO / l ----
  l_runA += __shfl_xor(l_runA, 16);
  l_runA += __shfl_xor(l_runA, 32);
  l_runB += __shfl_xor(l_runB, 16);
  l_runB += __shfl_xor(l_runB, 32);
  const float liA = 1.f / l_runA;
  const float liB = 1.f / l_runB;
  unsigned short* oA = ctxb + (size_t)((b << 11) + q0 + r0) * 1024 + (h << 6);
  unsigned short* oB = ctxb + (size_t)((b << 11) + q0 + r1) * 1024 + (h << 6);
  #pragma unroll
  for (int mt = 0; mt < 4; mt++){
    ushort4 o;
    o.x = f2bf(accA[mt][0] * liA);
    o.y = f2bf(accA[mt][1] * liA);
    o.z = f2bf(accA[mt][2] * liA);
    o.w = f2bf(accA[mt][3] * liA);
    *(ushort4*)&oA[(mt << 4) + (quad << 2)] = o;
    o.x = f2bf(accB[mt][0] * liB);
    o.y = f2bf(accB[mt][1] * liB);
    o.z = f2bf(accB[mt][2] * liB);
    o.w = f2bf(accB[mt][3] * liB);
    *(ushort4*)&oB[(mt << 4) + (quad << 2)] = o;
  }
}

// ---------------- residual + LayerNorm (1024 cols, one block per row); a is bf16 ----------------
__global__ void __launch_bounds__(256) k_ln(const unsigned short* __restrict__ a,
                                            const float* __restrict__ res,
                                            const float* __restrict__ gg, const float* __restrict__ bb,
                                            float* __restrict__ out, unsigned short* __restrict__ outb){
  const int row = blockIdx.x, t = threadIdx.x;
  const ushort4 au = ((const ushort4*)(a + (size_t)row * 1024))[t];
  const float4 rv = ((const float4*)(res + (size_t)row * 1024))[t];
  float4 v;
  { union { unsigned u; float f; } c;
    c.u = (unsigned)au.x << 16; v.x = c.f + rv.x;
    c.u = (unsigned)au.y << 16; v.y = c.f + rv.y;
    c.u = (unsigned)au.z << 16; v.z = c.f + rv.z;
    c.u = (unsigned)au.w << 16; v.w = c.f + rv.w; }
  float sum = v.x + v.y + v.z + v.w;
  float ss  = v.x * v.x + v.y * v.y + v.z * v.z + v.w * v.w;
  #pragma unroll
  for (int off = 32; off > 0; off >>= 1){
    sum += __shfl_down(sum, off);
    ss  += __shfl_down(ss, off);
  }
  __shared__ float red[8];
  const int w = t >> 6;
  if ((t & 63) == 0){ red[w] = sum; red[4 + w] = ss; }
  __syncthreads();
  const float S  = red[0] + red[1] + red[2] + red[3];
  const float SS = red[4] + red[5] + red[6] + red[7];
  const float mu  = S * (1.f / 1024.f);
  const float var = SS * (1.f / 1024.f) - mu * mu;
  const float rs  = rsqrtf(var + 1e-5f);
  const float4 gv = ((const float4*)gg)[t];
  const float4 bv = ((const float4*)bb)[t];
  float4 o;
  o.x = (v.x - mu) * rs * gv.x + bv.x;
  o.y = (v.y - mu) * rs * gv.y + bv.y;
  o.z = (v.z - mu) * rs * gv.z + bv.z;
  o.w = (v.w - mu) * rs * gv.w + bv.w;
  ((float4*)(out + (size_t)row * 1024))[t] = o;
  if (outb){
    ushort4 ob; ob.x = f2bf(o.x); ob.y = f2bf(o.y); ob.z = f2bf(o.z); ob.w = f2bf(o.w);
    ((ushort4*)(outb + (size_t)row * 1024))[t] = ob;
  }
}

extern "C" void kernel_launch(void* const* d_in, const int* in_sizes, int n_in,
                              void* d_out, int out_size, void* d_ws, size_t ws_size,
                              hipStream_t stream){
  const float* x     = (const float*)d_in[0];
  const int*   amask = (const int*)d_in[1];
  const float* Wq    = (const float*)d_in[2];
  const float* bq    = (const float*)d_in[3];
  const float* Wk    = (const float*)d_in[4];
  const float* bk    = (const float*)d_in[5];
  const float* Wv    = (const float*)d_in[6];
  const float* bv    = (const float*)d_in[7];
  const float* Wo    = (const float*)d_in[8];
  const float* bo    = (const float*)d_in[9];
  const float* g1    = (const float*)d_in[10];
  const float* b1    = (const float*)d_in[11];
  const float* W1    = (const float*)d_in[12];
  const float* bias1 = (const float*)d_in[13];
  const float* W2    = (const float*)d_in[14];
  const float* bias2 = (const float*)d_in[15];
  const float* g2    = (const float*)d_in[16];
  const float* b2    = (const float*)d_in[17];

  char* ws = (char*)d_ws;
  unsigned short* xb    = (unsigned short*)(ws + 0);            //  8 MB
  unsigned short* wqkvt = (unsigned short*)(ws + 8388608);      //  6 MB
  float*          qbias = (float*)         (ws + 14680064);     // 12 KB
  unsigned short* wot   = (unsigned short*)(ws + 14692352);     //  2 MB
  unsigned short* w1t   = (unsigned short*)(ws + 16789504);     //  4 MB
  unsigned short* w2t   = (unsigned short*)(ws + 20983808);     //  4 MB
  unsigned short* ctxb  = (unsigned short*)(ws + 25178112);     //  8 MB
  unsigned short* attnb = (unsigned short*)(ws + 33566720);     //  8 MB bf16 (Wo out; later FFN2 out)
  unsigned short* fbufb = attnb;
  unsigned short* qkvb  = (unsigned short*)(ws + 50343936);     // 24 MB: QKV bf16 [4096][3072]
  float*          out1  = (float*)         (ws + 50343936);     // 16 MB fp32, reuse (qkvb dead after attn)
  unsigned short* out1b = (unsigned short*)(ws + 50343936 + 25165824);  // 8 MB
  unsigned short* h1    = (unsigned short*)(ws + 50343936 + 33554432);  // 16 MB

  // --- prep (2 kernels) ---
  k_cvt_qb<<<dim3(4108), dim3(256), 0, stream>>>(x, xb, bq, bk, bv, qbias);
  k_prep_w<<<dim3(8192), dim3(256), 0, stream>>>(Wo, W1, W2, Wq, Wk, Wv, wot, w1t, w2t, wqkvt);

  // --- QKV projection -> bf16 (Q pre-scaled by 0.125*log2e via Wq/bq): 768 blocks = 3/CU ---
  k_gemm128<0,1><<<dim3(24, 32), dim3(256), 0, stream>>>(xb, wqkvt, qbias, qkvb, 3072, 1024);
  // --- MFMA flash attention v9: in-register P + dbuf K/V, 1 barrier/tile -> ctxb bf16 ---
  k_attn<<<dim3(16, 32), dim3(256), 0, stream>>>(qkvb, amask, ctxb);
  // --- output projection: 128x64 tile -> 512 blocks = 2/CU, bf16 out ---
  k_gemm64n<0,1><<<dim3(16, 32), dim3(256), 0, stream>>>(ctxb, wot, bo, attnb, MDIM, 1024);
  // --- LN1(attnb + x) -> out1 fp32 + out1b bf16 ---
  k_ln<<<dim3(4096), dim3(256), 0, stream>>>(attnb, x, g1, b1, out1, out1b);
  // --- FFN ---
  k_gemm128<1,1><<<dim3(16, 32), dim3(256), 0, stream>>>(out1b, w1t, bias1, h1, FFH, 1024);
  k_gemm64n<0,1><<<dim3(16, 32), dim3(256), 0, stream>>>(h1, w2t, bias2, fbufb, MDIM, 2048);
  // --- LN2(fbufb + out1) -> d_out ---
  k_ln<<<dim3(4096), dim3(256), 0, stream>>>(fbufb, out1, g2, b2, (float*)d_out, nullptr);
}

// Round 3
// 303.783 us; speedup vs baseline: 1.1107x; 1.0289x over previous
//
#include <hip/hip_runtime.h>

#define MDIM 1024
#define FFH  2048
#define SEQ  2048
#define AST  72    // Ks row stride (shorts): 144 B, 16B multiple (16B alignment mandatory: R6/R7)
#define VST  136   // Vt row stride (128 keys + 8 pad): 272 B, 16B multiple
#define QSCL 0.18033688f   // 0.125 * log2(e): scores exit MFMA in log2 domain -> raw v_exp_f32

// exp2f libcall carries a denormal-fixup sequence (R10: attn VALUBusy 46.8->55.6, +9us).
#if __has_builtin(__builtin_amdgcn_exp2f)
  #define EXP2(x) __builtin_amdgcn_exp2f(x)
#else
  #define EXP2(x) exp2f(x)
#endif

typedef __attribute__((ext_vector_type(8))) __bf16 bf16x8;
typedef __attribute__((ext_vector_type(4))) float floatx4;
typedef __attribute__((ext_vector_type(8))) unsigned short ushort8;
typedef __attribute__((address_space(3))) unsigned int lds_uint;
typedef const __attribute__((address_space(1))) unsigned int g_uint;

__device__ __forceinline__ unsigned short f2bf(float f){
  union { float f; unsigned u; } v; v.f = f;
  unsigned u = v.u;
  u += 0x7fffu + ((u >> 16) & 1u);
  return (unsigned short)(u >> 16);
}
__device__ __forceinline__ unsigned short f2bf_tr(float f){   // truncating (P >= 0, softmax-internal)
  union { float f; unsigned u; } v; v.f = f;
  return (unsigned short)(v.u >> 16);
}

// ---------------- prep kernel 1: x -> bf16 (blocks 0..4095) + qbias build (blocks 4096..4107) ----------------
__global__ void k_cvt_qb(const float* __restrict__ x, unsigned short* __restrict__ xb,
                         const float* __restrict__ bq, const float* __restrict__ bk,
                         const float* __restrict__ bv, float* __restrict__ qbias){
  const int bid = blockIdx.x, t = threadIdx.x;
  if (bid < 4096){
    int i = (bid * 256 + t) * 4;
    float4 v = *(const float4*)(x + i);
    ushort4 o;
    o.x = f2bf(v.x); o.y = f2bf(v.y); o.z = f2bf(v.z); o.w = f2bf(v.w);
    *(ushort4*)(xb + i) = o;
  } else {
    int i = (bid - 4096) * 256 + t;   // 0..3071
    qbias[i] = (i < 1024) ? bq[i] * QSCL : (i < 2048) ? bk[i - 1024] : bv[i - 2048];
  }
}

// ---------------- prep kernel 2: all weight transposes (block-uniform branches) ----------------
// bid <1024: Wo[1024][1024]->wot | <3072: W1[1024][2048]->w1t | <5120: W2[2048][1024]->w2t
// | <8192: Wq/Wk/Wv [16][1024][64] -> fused wqkvt [3072][1024] (Wq pre-scaled QSCL)
__global__ void __launch_bounds__(256) k_prep_w(const float* __restrict__ Wo, const float* __restrict__ W1,
                                                const float* __restrict__ W2, const float* __restrict__ Wq,
                                                const float* __restrict__ Wk, const float* __restrict__ Wv,
                                                unsigned short* __restrict__ wot, unsigned short* __restrict__ w1t,
                                                unsigned short* __restrict__ w2t, unsigned short* __restrict__ wqkvt){
  __shared__ unsigned short Ts[32 * 36];
  const int t = threadIdx.x, bid = blockIdx.x;
  const int lr = t >> 3, lc4 = (t & 7) << 2;
  if (bid >= 5120){
    const int id = bid - 5120;                  // [0,3072)
    const int xm = id & 31, yd = (id >> 5) & 1, z = id >> 6;   // z in [0,48)
    const int tensor = z >> 4, h = z & 15;
    const float* W = (tensor == 0) ? Wq : (tensor == 1) ? Wk : Wv;
    const float scl = (tensor == 0) ? QSCL : 1.0f;
    const int m0 = xm << 5, d0 = yd << 5;
    float4 v = *(const float4*)(W + ((size_t)h << 16) + (size_t)(m0 + lr) * 64 + d0 + lc4);
    ushort4 o; o.x = f2bf(v.x * scl); o.y = f2bf(v.y * scl); o.z = f2bf(v.z * scl); o.w = f2bf(v.w * scl);
    *(ushort4*)&Ts[lr * 36 + lc4] = o;
    __syncthreads();
    ushort4 w;
    w.x = Ts[(lc4 + 0) * 36 + lr];
    w.y = Ts[(lc4 + 1) * 36 + lr];
    w.z = Ts[(lc4 + 2) * 36 + lr];
    w.w = Ts[(lc4 + 3) * 36 + lr];
    const int n = (tensor << 10) + (h << 6) + d0 + lr;
    *(ushort4*)(wqkvt + ((size_t)n << 10) + m0 + lc4) = w;
    return;
  }
  const float* src; unsigned short* dst; int K, N, k0, n0;
  if (bid < 1024){
    src = Wo; dst = wot; K = 1024; N = 1024;
    n0 = (bid & 31) << 5; k0 = (bid >> 5) << 5;
  } else if (bid < 3072){
    const int id = bid - 1024;
    src = W1; dst = w1t; K = 1024; N = 2048;
    n0 = (id & 63) << 5; k0 = (id >> 6) << 5;
  } else {
    const int id = bid - 3072;
    src = W2; dst = w2t; K = 2048; N = 1024;
    n0 = (id & 31) << 5; k0 = (id >> 5) << 5;
  }
  float4 v = *(const float4*)(src + (size_t)(k0 + lr) * N + n0 + lc4);
  ushort4 o; o.x = f2bf(v.x); o.y = f2bf(v.y); o.z = f2bf(v.z); o.w = f2bf(v.w);
  *(ushort4*)&Ts[lr * 36 + lc4] = o;
  __syncthreads();
  ushort4 w;
  w.x = Ts[(lc4 + 0) * 36 + lr];
  w.y = Ts[(lc4 + 1) * 36 + lr];
  w.z = Ts[(lc4 + 2) * 36 + lr];
  w.w = Ts[(lc4 + 3) * 36 + lr];
  *(ushort4*)(dst + (size_t)(n0 + lr) * K + k0 + lc4) = w;
}

// ---------------- bf16 MFMA GEMM v2, 128x128 tile, BK=64, double-buffered LDS ----------------
// v1 exposed the staging drain serially: stage -> sync(vmcnt0 drain) -> compute -> sync (2 barriers,
// load latency on the critical path, hidden only by 2-3 blocks/CU TLP). v2 (T3-minimum, m248v2):
// issue next tile's gload_lds BEFORE compute; single end-of-step __syncthreads (its implicit
// vmcnt(0) drain lands after ~160+cy of MFMA -> latency hidden; barrier count halves).
// LDS 64 KB -> 2 blocks/CU (m99/m100: ~neutral trade; net win when drain-limited).
template<int RELU, int OUTBF>
__global__ void __launch_bounds__(256) k_gemm128(const unsigned short* __restrict__ A,
                                                 const unsigned short* __restrict__ Bt,
                                                 const float* __restrict__ bias,
                                                 void* __restrict__ Cout, int N, int K){
  __shared__ unsigned short As[2][2 * 128 * 32];
  __shared__ unsigned short Bs[2][2 * 128 * 32];
  const int t = threadIdx.x;
  const int m0 = blockIdx.y << 7, n0 = blockIdx.x << 7;
  const int lane = t & 63, w = t >> 6;
  const int quad = lane >> 4, l16 = lane & 15;
  const int mw = (w & 1) << 6, nw = (w >> 1) << 6;
  floatx4 acc[4][4];
  #pragma unroll
  for (int i = 0; i < 4; i++)
    #pragma unroll
    for (int j = 0; j < 4; j++) acc[i][j] = (floatx4){0.f, 0.f, 0.f, 0.f};
  const unsigned short* Ag  = A  + (size_t)(m0 + (t >> 2)) * K + ((t & 3) << 3);
  const unsigned short* Ag2 = Ag + (size_t)64 * K;
  const unsigned short* Bg  = Bt + (size_t)(n0 + (t >> 2)) * K + ((t & 3) << 3);
  const unsigned short* Bg2 = Bg + (size_t)64 * K;

#define STG128(Ad, Bd, kb) { \
    _Pragma("unroll") \
    for (int s = 0; s < 2; s++){ \
      const int ko = (kb) + (s << 5), lo = (s << 12) + (t << 3); \
      __builtin_amdgcn_global_load_lds((g_uint*)(Ag  + ko), (lds_uint*)&(Ad)[lo],        16, 0, 0); \
      __builtin_amdgcn_global_load_lds((g_uint*)(Ag2 + ko), (lds_uint*)&(Ad)[lo + 2048], 16, 0, 0); \
      __builtin_amdgcn_global_load_lds((g_uint*)(Bg  + ko), (lds_uint*)&(Bd)[lo],        16, 0, 0); \
      __builtin_amdgcn_global_load_lds((g_uint*)(Bg2 + ko), (lds_uint*)&(Bd)[lo + 2048], 16, 0, 0); \
    } }

  STG128(As[0], Bs[0], 0);
  __syncthreads();
  int cur = 0;
  for (int kb = 0; kb < K; kb += 64){
    if (kb + 64 < K) STG128(As[cur ^ 1], Bs[cur ^ 1], kb + 64);
    const unsigned short* Ar = As[cur];
    const unsigned short* Br = Bs[cur];
    #pragma unroll
    for (int s = 0; s < 2; s++){
      const int sb = s << 12;
      bf16x8 af[4], bf[4];
      #pragma unroll
      for (int mt = 0; mt < 4; mt++)
        af[mt] = *(const bf16x8*)&Ar[sb + ((mw + (mt << 4) + l16) << 5) + (quad << 3)];
      #pragma unroll
      for (int nt = 0; nt < 4; nt++)
        bf[nt] = *(const bf16x8*)&Br[sb + ((nw + (nt << 4) + l16) << 5) + (quad << 3)];
      #pragma unroll
      for (int mt = 0; mt < 4; mt++)
        #pragma unroll
        for (int nt = 0; nt < 4; nt++)
          acc[mt][nt] = __builtin_amdgcn_mfma_f32_16x16x32_bf16(af[mt], bf[nt], acc[mt][nt], 0, 0, 0);
    }
    __syncthreads();
    cur ^= 1;
  }
#undef STG128
  #pragma unroll
  for (int nt = 0; nt < 4; nt++){
    const int col = n0 + nw + (nt << 4) + l16;
    const float bsv = bias[col];
    #pragma unroll
    for (int mt = 0; mt < 4; mt++){
      const int row = m0 + mw + (mt << 4) + (quad << 2);
      #pragma unroll
      for (int r = 0; r < 4; r++){
        float v = acc[mt][nt][r] + bsv;
        if (RELU) v = fmaxf(v, 0.f);
        if (OUTBF) ((unsigned short*)Cout)[(size_t)(row + r) * N + col] = f2bf(v);
        else       ((float*)Cout)[(size_t)(row + r) * N + col] = v;
      }
    }
  }
}

// ---------------- bf16 MFMA GEMM v2, 128x64 tile, BK=64, double-buffered LDS (Wo/FFN2) ----------------
// Same T3-minimum restructure as k_gemm128 v2. LDS 48 KB; grid-limited at 2 blocks/CU anyway.
template<int RELU, int OUTBF>
__global__ void __launch_bounds__(256) k_gemm64n(const unsigned short* __restrict__ A,
                                                 const unsigned short* __restrict__ Bt,
                                                 const float* __restrict__ bias,
                                                 void* __restrict__ Cout, int N, int K){
  __shared__ unsigned short As[2][2 * 128 * 32];
  __shared__ unsigned short Bs[2][2 * 64 * 32];
  const int t = threadIdx.x;
  const int m0 = blockIdx.y << 7, n0 = blockIdx.x << 6;
  const int lane = t & 63, w = t >> 6;
  const int quad = lane >> 4, l16 = lane & 15;
  const int mw = (w & 1) << 6, nw = (w >> 1) << 5;
  floatx4 acc[4][2];
  #pragma unroll
  for (int i = 0; i < 4; i++)
    #pragma unroll
    for (int j = 0; j < 2; j++) acc[i][j] = (floatx4){0.f, 0.f, 0.f, 0.f};
  const unsigned short* Ag  = A  + (size_t)(m0 + (t >> 2)) * K + ((t & 3) << 3);
  const unsigned short* Ag2 = Ag + (size_t)64 * K;
  const unsigned short* Bg  = Bt + (size_t)(n0 + (t >> 2)) * K + ((t & 3) << 3);

#define STG64(Ad, Bd, kb) { \
    _Pragma("unroll") \
    for (int s = 0; s < 2; s++){ \
      const int ko = (kb) + (s << 5); \
      __builtin_amdgcn_global_load_lds((g_uint*)(Ag  + ko), (lds_uint*)&(Ad)[(s << 12) + (t << 3)],        16, 0, 0); \
      __builtin_amdgcn_global_load_lds((g_uint*)(Ag2 + ko), (lds_uint*)&(Ad)[(s << 12) + (t << 3) + 2048], 16, 0, 0); \
      __builtin_amdgcn_global_load_lds((g_uint*)(Bg  + ko), (lds_uint*)&(Bd)[(s << 11) + (t << 3)],        16, 0, 0); \
    } }

  STG64(As[0], Bs[0], 0);
  __syncthreads();
  int cur = 0;
  for (int kb = 0; kb < K; kb += 64){
    if (kb + 64 < K) STG64(As[cur ^ 1], Bs[cur ^ 1], kb + 64);
    const unsigned short* Ar = As[cur];
    const unsigned short* Br = Bs[cur];
    #pragma unroll
    for (int s = 0; s < 2; s++){
      bf16x8 af[4], bf[2];
      #pragma unroll
      for (int mt = 0; mt < 4; mt++)
        af[mt] = *(const bf16x8*)&Ar[(s << 12) + ((mw + (mt << 4) + l16) << 5) + (quad << 3)];
      #pragma unroll
      for (int nt = 0; nt < 2; nt++)
        bf[nt] = *(const bf16x8*)&Br[(s << 11) + ((nw + (nt << 4) + l16) << 5) + (quad << 3)];
      #pragma unroll
      for (int mt = 0; mt < 4; mt++)
        #pragma unroll
        for (int nt = 0; nt < 2; nt++)
          acc[mt][nt] = __builtin_amdgcn_mfma_f32_16x16x32_bf16(af[mt], bf[nt], acc[mt][nt], 0, 0, 0);
    }
    __syncthreads();
    cur ^= 1;
  }
#undef STG64
  #pragma unroll
  for (int nt = 0; nt < 2; nt++){
    const int col = n0 + nw + (nt << 4) + l16;
    const float bsv = bias[col];
    #pragma unroll
    for (int mt = 0; mt < 4; mt++){
      const int row = m0 + mw + (mt << 4) + (quad << 2);
      #pragma unroll
      for (int r = 0; r < 4; r++){
        float v = acc[mt][nt][r] + bsv;
        if (RELU) v = fmaxf(v, 0.f);
        if (OUTBF) ((unsigned short*)Cout)[(size_t)(row + r) * N + col] = f2bf(v);
        else       ((float*)Cout)[(size_t)(row + r) * N + col] = v;
      }
    }
  }
}

// ---------------- MFMA flash attention v9: in-register P (sigma-permuted V cols) + K/V dbuf ----------------
// v8 post-mortem: LDS-bound incl. ~450 conflict cy/wave-tile (V transpose-writes 8-way) + P LDS
// round-trip (24 ops + serial chain). v9:
//  (a) P never touches LDS: key-permutation sigma(32s+8q+j) = 32s+16*(j>>2)+4q+(j&3) applied to
//      Vt COLUMNS makes the PV B-fragment exactly lane-local (QK output regs j of groups 2s,2s+1).
//  (b) Vt block-XOR swizzle: 16B-block' = block ^ ((d_row>>4)&3). Write-side spreads banks
//      (2-way, free); read-side XOR is constant per instruction (mt) -> balance unchanged.
//  (c) K/V double-buffered (PQs freed) -> ONE barrier per tile: write t+1 into buf^1 while
//      computing buf c; end-of-tile barrier gives visibility + WAR protection.
//  (d) l_run cross-quad shuffles deferred to epilogue (no running max -> sum is linear).
__global__ void __launch_bounds__(256, 2) k_attn(const unsigned short* __restrict__ qkvb,
                                                 const int* __restrict__ amask,
                                                 unsigned short* __restrict__ ctxb){
  __shared__ __align__(16) unsigned short Ks[2][128 * AST];   // [key][d]  2x 18.4 KB
  __shared__ __align__(16) unsigned short Vt[2][64 * VST];    // [d][key'] 2x 17.4 KB
  __shared__ __align__(16) int msk[2][128];
  const int t = threadIdx.x;                 // 0..255
  const int w = t >> 6, lane = t & 63;       // w: 0..3
  const int quad = lane >> 4, l16 = lane & 15;
  const int b = blockIdx.y >> 4, h = blockIdx.y & 15;
  const int q0 = blockIdx.x << 7;            // 128-row q tile
  const int r0 = (w << 5) + l16;             // qc=0 row of this lane (0..127)
  const int r1 = r0 + 16;                    // qc=1 row
  const int sr = t >> 2, sc = (t & 3) << 4;  // K staging: rows sr, sr+64; 16-short chunk
  const int kg = t >> 4, dc = (t & 15) << 2; // V staging: 4-key groups kg, kg+16; 4-d chunk
  // sigma + bank-swizzle constants for V staging (keys 4kg+i -> phys col pc0+i; +64 for kg+16)
  const int swz  = (dc >> 4) & 3;                        // = (row>>4)&3, constant per thread
  const int pc0  = ((((kg & 3) | ((kg >> 3) << 2)) ^ swz) << 3) | (((kg >> 2) & 1) << 2);

  // ---- Q stage via Ks[0] (one-time) ----
  {
    const int qr = t >> 1, qc = (t & 1) << 5;
    const unsigned short* qs = qkvb + (size_t)((b << 11) + q0 + qr) * 3072 + (h << 6) + qc;
    unsigned short* qd = &Ks[0][qr * AST + qc];
    *(uint4*)(qd)      = *(const uint4*)(qs);
    *(uint4*)(qd + 8)  = *(const uint4*)(qs + 8);
    *(uint4*)(qd + 16) = *(const uint4*)(qs + 16);
    *(uint4*)(qd + 24) = *(const uint4*)(qs + 24);
  }
  __syncthreads();
  const bf16x8 qa0 = *(const bf16x8*)&Ks[0][r0 * AST + (quad << 3)];
  const bf16x8 qa1 = *(const bf16x8*)&Ks[0][r0 * AST + (quad << 3) + 32];
  const bf16x8 qb0 = *(const bf16x8*)&Ks[0][r1 * AST + (quad << 3)];
  const bf16x8 qb1 = *(const bf16x8*)&Ks[0][r1 * AST + (quad << 3) + 32];

  floatx4 accA[4], accB[4];
  #pragma unroll
  for (int i = 0; i < 4; i++){
    accA[i] = (floatx4){0.f, 0.f, 0.f, 0.f};
    accB[i] = (floatx4){0.f, 0.f, 0.f, 0.f};
  }
  float l_runA = 0.f, l_runB = 0.f;

  const unsigned short* kbase  = qkvb + (size_t)((b << 11) + sr) * 3072 + 1024 + (h << 6) + sc;
  const unsigned short* kbase2 = kbase + (size_t)64 * 3072;
  const unsigned short* vbase  = qkvb + (size_t)((b << 11) + (kg << 2)) * 3072 + 2048 + (h << 6) + dc;
  const unsigned short* vbase2 = vbase + (size_t)64 * 3072;
  const int* mbase = amask + (b << 11);

  uint4 krA, krB, krC, krD;
  ushort4 va0, va1, va2, va3, vb0, vb1, vb2, vb3;
  int mreg = 1;

#define LOADT(tt) { \
    const size_t off = (size_t)((tt) << 7) * 3072; \
    krA = *(const uint4*)(kbase + off); \
    krB = *(const uint4*)(kbase + off + 8); \
    krC = *(const uint4*)(kbase2 + off); \
    krD = *(const uint4*)(kbase2 + off + 8); \
    va0 = *(const ushort4*)(vbase + off); \
    va1 = *(const ushort4*)(vbase + off + 3072); \
    va2 = *(const ushort4*)(vbase + off + 2 * 3072); \
    va3 = *(const ushort4*)(vbase + off + 3 * 3072); \
    vb0 = *(const ushort4*)(vbase2 + off); \
    vb1 = *(const ushort4*)(vbase2 + off + 3072); \
    vb2 = *(const ushort4*)(vbase2 + off + 2 * 3072); \
    vb3 = *(const ushort4*)(vbase2 + off + 3 * 3072); \
    if (t < 128) mreg = mbase[((tt) << 7) + t]; \
  }

#define STORET(dst) { \
    unsigned short* Kd = Ks[dst]; \
    unsigned short* Vd = Vt[dst]; \
    *(uint4*)&Kd[sr * AST + sc]            = krA; \
    *(uint4*)&Kd[sr * AST + sc + 8]        = krB; \
    *(uint4*)&Kd[(sr + 64) * AST + sc]     = krC; \
    *(uint4*)&Kd[(sr + 64) * AST + sc + 8] = krD; \
    ushort4 cc; \
    cc.x = va0.x; cc.y = va1.x; cc.z = va2.x; cc.w = va3.x; *(ushort4*)&Vd[(dc + 0) * VST + pc0] = cc; \
    cc.x = va0.y; cc.y = va1.y; cc.z = va2.y; cc.w = va3.y; *(ushort4*)&Vd[(dc + 1) * VST + pc0] = cc; \
    cc.x = va0.z; cc.y = va1.z; cc.z = va2.z; cc.w = va3.z; *(ushort4*)&Vd[(dc + 2) * VST + pc0] = cc; \
    cc.x = va0.w; cc.y = va1.w; cc.z = va2.w; cc.w = va3.w; *(ushort4*)&Vd[(dc + 3) * VST + pc0] = cc; \
    cc.x = vb0.x; cc.y = vb1.x; cc.z = vb2.x; cc.w = vb3.x; *(ushort4*)&Vd[(dc + 0) * VST + pc0 + 64] = cc; \
    cc.x = vb0.y; cc.y = vb1.y; cc.z = vb2.y; cc.w = vb3.y; *(ushort4*)&Vd[(dc + 1) * VST + pc0 + 64] = cc; \
    cc.x = vb0.z; cc.y = vb1.z; cc.z = vb2.z; cc.w = vb3.z; *(ushort4*)&Vd[(dc + 2) * VST + pc0 + 64] = cc; \
    cc.x = vb0.w; cc.y = vb1.w; cc.z = vb2.w; cc.w = vb3.w; *(ushort4*)&Vd[(dc + 3) * VST + pc0 + 64] = cc; \
    if (t < 128) msk[dst][t] = mreg; \
  }

  // ---- prologue: tile0 -> buf0; issue tile1 prefetch ----
  LOADT(0);
  __syncthreads();            // Q fragment reads complete before Ks[0] overwrite
  STORET(0);
  LOADT(1);
  __syncthreads();            // buf0 staging visible

  int c = 0;
  for (int kt = 0; kt < 16; kt++){
    if (kt + 1 < 16) STORET(c ^ 1);       // write prefetched tile kt+1 into other buffer
    if (kt + 2 < 16) LOADT(kt + 2);       // issue global loads for tile kt+2
    {
      const unsigned short* Kc = Ks[c];
      const unsigned short* Vc = Vt[c];
      const int* Mc = msk[c];
      float lsA = 0.f, lsB = 0.f;
      #pragma unroll
      for (int s = 0; s < 4; s++){
        // ---- QK^T for key groups g0=2s (rows 32s..), g1=2s+1 (rows 32s+16..) ----
        const unsigned short* kp = &Kc[((s << 5) + l16) * AST + (quad << 3)];
        const bf16x8 k00 = *(const bf16x8*)(kp);
        const bf16x8 k01 = *(const bf16x8*)(kp + 32);
        const bf16x8 k10 = *(const bf16x8*)(kp + (AST << 4));
        const bf16x8 k11 = *(const bf16x8*)(kp + (AST << 4) + 32);
        floatx4 sA0 = (floatx4){0.f, 0.f, 0.f, 0.f};
        floatx4 sB0 = (floatx4){0.f, 0.f, 0.f, 0.f};
        floatx4 sA1 = (floatx4){0.f, 0.f, 0.f, 0.f};
        floatx4 sB1 = (floatx4){0.f, 0.f, 0.f, 0.f};
        __builtin_amdgcn_s_setprio(1);
        sA0 = __builtin_amdgcn_mfma_f32_16x16x32_bf16(k00, qa0, sA0, 0, 0, 0);
        sA0 = __builtin_amdgcn_mfma_f32_16x16x32_bf16(k01, qa1, sA0, 0, 0, 0);
        sB0 = __builtin_amdgcn_mfma_f32_16x16x32_bf16(k00, qb0, sB0, 0, 0, 0);
        sB0 = __builtin_amdgcn_mfma_f32_16x16x32_bf16(k01, qb1, sB0, 0, 0, 0);
        sA1 = __builtin_amdgcn_mfma_f32_16x16x32_bf16(k10, qa0, sA1, 0, 0, 0);
        sA1 = __builtin_amdgcn_mfma_f32_16x16x32_bf16(k11, qa1, sA1, 0, 0, 0);
        sB1 = __builtin_amdgcn_mfma_f32_16x16x32_bf16(k10, qb0, sB1, 0, 0, 0);
        sB1 = __builtin_amdgcn_mfma_f32_16x16x32_bf16(k11, qb1, sB1, 0, 0, 0);
        __builtin_amdgcn_s_setprio(0);
        // ---- masked exp (log2 domain) ----
        const int4 m0 = *(const int4*)&Mc[(s << 5) + (quad << 2)];
        const int4 m1 = *(const int4*)&Mc[(s << 5) + 16 + (quad << 2)];
        const float a0 = m0.x ? EXP2(sA0[0]) : 0.f;
        const float a1 = m0.y ? EXP2(sA0[1]) : 0.f;
        const float a2 = m0.z ? EXP2(sA0[2]) : 0.f;
        const float a3 = m0.w ? EXP2(sA0[3]) : 0.f;
        const float a4 = m1.x ? EXP2(sA1[0]) : 0.f;
        const float a5 = m1.y ? EXP2(sA1[1]) : 0.f;
        const float a6 = m1.z ? EXP2(sA1[2]) : 0.f;
        const float a7 = m1.w ? EXP2(sA1[3]) : 0.f;
        const float b0 = m0.x ? EXP2(sB0[0]) : 0.f;
        const float b1 = m0.y ? EXP2(sB0[1]) : 0.f;
        const float b2 = m0.z ? EXP2(sB0[2]) : 0.f;
        const float b3 = m0.w ? EXP2(sB0[3]) : 0.f;
        const float b4 = m1.x ? EXP2(sB1[0]) : 0.f;
        const float b5 = m1.y ? EXP2(sB1[1]) : 0.f;
        const float b6 = m1.z ? EXP2(sB1[2]) : 0.f;
        const float b7 = m1.w ? EXP2(sB1[3]) : 0.f;
        lsA += (a0 + a1) + (a2 + a3) + (a4 + a5) + (a6 + a7);
        lsB += (b0 + b1) + (b2 + b3) + (b4 + b5) + (b6 + b7);
        // ---- pack P fragments, lane-local by sigma: slots 0-3 <- g0 regs, 4-7 <- g1 regs ----
        ushort8 uA, uB;
        uA[0] = f2bf_tr(a0); uA[1] = f2bf_tr(a1); uA[2] = f2bf_tr(a2); uA[3] = f2bf_tr(a3);
        uA[4] = f2bf_tr(a4); uA[5] = f2bf_tr(a5); uA[6] = f2bf_tr(a6); uA[7] = f2bf_tr(a7);
        uB[0] = f2bf_tr(b0); uB[1] = f2bf_tr(b1); uB[2] = f2bf_tr(b2); uB[3] = f2bf_tr(b3);
        uB[4] = f2bf_tr(b4); uB[5] = f2bf_tr(b5); uB[6] = f2bf_tr(b6); uB[7] = f2bf_tr(b7);
        const bf16x8 pfA = __builtin_bit_cast(bf16x8, uA);
        const bf16x8 pfB = __builtin_bit_cast(bf16x8, uB);
        // ---- PV: O^T[d][q] += V^T[d][sigma(k)]*P^T[sigma(k)][q] ----
        __builtin_amdgcn_s_setprio(1);
        #pragma unroll
        for (int mt = 0; mt < 4; mt++){
          const bf16x8 vf = *(const bf16x8*)&Vc[((mt << 4) + l16) * VST + ((((s << 2) + quad) ^ mt) << 3)];
          accA[mt] = __builtin_amdgcn_mfma_f32_16x16x32_bf16(vf, pfA, accA[mt], 0, 0, 0);
          accB[mt] = __builtin_amdgcn_mfma_f32_16x16x32_bf16(vf, pfB, accB[mt], 0, 0, 0);
        }
        __builtin_amdgcn_s_setprio(0);
      }
      l_runA += lsA;
      l_runB += lsB;
    }
    __syncthreads();           // buf c readers done + buf c^1 staging visible
    c ^= 1;
  }
#undef LOADT
#undef STORET

  // ---- epilogue: deferred cross-quad l reduction, then O[q][d] = accO / l ----
  l_runA += __shfl_xor(l_runA, 16);
  l_runA += __shfl_xor(l_runA, 32);
  l_runB += __shfl_xor(l_runB, 16);
  l_runB += __shfl_xor(l_runB, 32);
  const float liA = 1.f / l_runA;
  const float liB = 1.f / l_runB;
  unsigned short* oA = ctxb + (size_t)((b << 11) + q0 + r0) * 1024 + (h << 6);
  unsigned short* oB = ctxb + (size_t)((b << 11) + q0 + r1) * 1024 + (h << 6);
  #pragma unroll
  for (int mt = 0; mt < 4; mt++){
    ushort4 o;
    o.x = f2bf(accA[mt][0] * liA);
    o.y = f2bf(accA[mt][1] * liA);
    o.z = f2bf(accA[mt][2] * liA);
    o.w = f2bf(accA[mt][3] * liA);
    *(ushort4*)&oA[(mt << 4) + (quad << 2)] = o;
    o.x = f2bf(accB[mt][0] * liB);
    o.y = f2bf(accB[mt][1] * liB);
    o.z = f2bf(accB[mt][2] * liB);
    o.w = f2bf(accB[mt][3] * liB);
    *(ushort4*)&oB[(mt << 4) + (quad << 2)] = o;
  }
}

// ---------------- residual + LayerNorm (1024 cols, one block per row); a is bf16 ----------------
__global__ void __launch_bounds__(256) k_ln(const unsigned short* __restrict__ a,
                                            const float* __restrict__ res,
                                            const float* __restrict__ gg, const float* __restrict__ bb,
                                            float* __restrict__ out, unsigned short* __restrict__ outb){
  const int row = blockIdx.x, t = threadIdx.x;
  const ushort4 au = ((const ushort4*)(a + (size_t)row * 1024))[t];
  const float4 rv = ((const float4*)(res + (size_t)row * 1024))[t];
  float4 v;
  { union { unsigned u; float f; } c;
    c.u = (unsigned)au.x << 16; v.x = c.f + rv.x;
    c.u = (unsigned)au.y << 16; v.y = c.f + rv.y;
    c.u = (unsigned)au.z << 16; v.z = c.f + rv.z;
    c.u = (unsigned)au.w << 16; v.w = c.f + rv.w; }
  float sum = v.x + v.y + v.z + v.w;
  float ss  = v.x * v.x + v.y * v.y + v.z * v.z + v.w * v.w;
  #pragma unroll
  for (int off = 32; off > 0; off >>= 1){
    sum += __shfl_down(sum, off);
    ss  += __shfl_down(ss, off);
  }
  __shared__ float red[8];
  const int w = t >> 6;
  if ((t & 63) == 0){ red[w] = sum; red[4 + w] = ss; }
  __syncthreads();
  const float S  = red[0] + red[1] + red[2] + red[3];
  const float SS = red[4] + red[5] + red[6] + red[7];
  const float mu  = S * (1.f / 1024.f);
  const float var = SS * (1.f / 1024.f) - mu * mu;
  const float rs  = rsqrtf(var + 1e-5f);
  const float4 gv = ((const float4*)gg)[t];
  const float4 bv = ((const float4*)bb)[t];
  float4 o;
  o.x = (v.x - mu) * rs * gv.x + bv.x;
  o.y = (v.y - mu) * rs * gv.y + bv.y;
  o.z = (v.z - mu) * rs * gv.z + bv.z;
  o.w = (v.w - mu) * rs * gv.w + bv.w;
  ((float4*)(out + (size_t)row * 1024))[t] = o;
  if (outb){
    ushort4 ob; ob.x = f2bf(o.x); ob.y = f2bf(o.y); ob.z = f2bf(o.z); ob.w = f2bf(o.w);
    ((ushort4*)(outb + (size_t)row * 1024))[t] = ob;
  }
}

extern "C" void kernel_launch(void* const* d_in, const int* in_sizes, int n_in,
                              void* d_out, int out_size, void* d_ws, size_t ws_size,
                              hipStream_t stream){
  const float* x     = (const float*)d_in[0];
  const int*   amask = (const int*)d_in[1];
  const float* Wq    = (const float*)d_in[2];
  const float* bq    = (const float*)d_in[3];
  const float* Wk    = (const float*)d_in[4];
  const float* bk    = (const float*)d_in[5];
  const float* Wv    = (const float*)d_in[6];
  const float* bv    = (const float*)d_in[7];
  const float* Wo    = (const float*)d_in[8];
  const float* bo    = (const float*)d_in[9];
  const float* g1    = (const float*)d_in[10];
  const float* b1    = (const float*)d_in[11];
  const float* W1    = (const float*)d_in[12];
  const float* bias1 = (const float*)d_in[13];
  const float* W2    = (const float*)d_in[14];
  const float* bias2 = (const float*)d_in[15];
  const float* g2    = (const float*)d_in[16];
  const float* b2    = (const float*)d_in[17];

  char* ws = (char*)d_ws;
  unsigned short* xb    = (unsigned short*)(ws + 0);            //  8 MB
  unsigned short* wqkvt = (unsigned short*)(ws + 8388608);      //  6 MB
  float*          qbias = (float*)         (ws + 14680064);     // 12 KB
  unsigned short* wot   = (unsigned short*)(ws + 14692352);     //  2 MB
  unsigned short* w1t   = (unsigned short*)(ws + 16789504);     //  4 MB
  unsigned short* w2t   = (unsigned short*)(ws + 20983808);     //  4 MB
  unsigned short* ctxb  = (unsigned short*)(ws + 25178112);     //  8 MB
  unsigned short* attnb = (unsigned short*)(ws + 33566720);     //  8 MB bf16 (Wo out; later FFN2 out)
  unsigned short* fbufb = attnb;
  unsigned short* qkvb  = (unsigned short*)(ws + 50343936);     // 24 MB: QKV bf16 [4096][3072]
  float*          out1  = (float*)         (ws + 50343936);     // 16 MB fp32, reuse (qkvb dead after attn)
  unsigned short* out1b = (unsigned short*)(ws + 50343936 + 25165824);  // 8 MB
  unsigned short* h1    = (unsigned short*)(ws + 50343936 + 33554432);  // 16 MB

  // --- prep (2 kernels) ---
  k_cvt_qb<<<dim3(4108), dim3(256), 0, stream>>>(x, xb, bq, bk, bv, qbias);
  k_prep_w<<<dim3(8192), dim3(256), 0, stream>>>(Wo, W1, W2, Wq, Wk, Wv, wot, w1t, w2t, wqkvt);

  // --- QKV projection -> bf16 (Q pre-scaled by 0.125*log2e via Wq/bq): 768 blocks = 3/CU ---
  k_gemm128<0,1><<<dim3(24, 32), dim3(256), 0, stream>>>(xb, wqkvt, qbias, qkvb, 3072, 1024);
  // --- MFMA flash attention v9: in-register P + dbuf K/V, 1 barrier/tile -> ctxb bf16 ---
  k_attn<<<dim3(16, 32), dim3(256), 0, stream>>>(qkvb, amask, ctxb);
  // --- output projection: 128x64 tile, dbuf -> 512 blocks = 2/CU, bf16 out ---
  k_gemm64n<0,1><<<dim3(16, 32), dim3(256), 0, stream>>>(ctxb, wot, bo, attnb, MDIM, 1024);
  // --- LN1(attnb + x) -> out1 fp32 + out1b bf16 ---
  k_ln<<<dim3(4096), dim3(256), 0, stream>>>(attnb, x, g1, b1, out1, out1b);
  // --- FFN ---
  k_gemm128<1,1><<<dim3(16, 32), dim3(256), 0, stream>>>(out1b, w1t, bias1, h1, FFH, 1024);
  k_gemm64n<0,1><<<dim3(16, 32), dim3(256), 0, stream>>>(h1, w2t, bias2, fbufb, MDIM, 2048);
  // --- LN2(fbufb + out1) -> d_out ---
  k_ln<<<dim3(4096), dim3(256), 0, stream>>>(fbufb, out1, g2, b2, (float*)d_out, nullptr);
}

// Round 5
// 297.168 us; speedup vs baseline: 1.1355x; 1.0223x over previous
//
#include <hip/hip_runtime.h>

#define MDIM 1024
#define FFH  2048
#define SEQ  2048
#define AST  72    // Ks row stride (shorts): 144 B, 16B multiple (16B alignment mandatory: R6/R7)
#define VST  136   // Vt row stride (128 keys + 8 pad): 272 B, 16B multiple
#define QSCL 0.18033688f   // 0.125 * log2(e): scores exit MFMA in log2 domain -> raw v_exp_f32

// exp2f libcall carries a denormal-fixup sequence (R10: attn VALUBusy 46.8->55.6, +9us).
#if __has_builtin(__builtin_amdgcn_exp2f)
  #define EXP2(x) __builtin_amdgcn_exp2f(x)
#else
  #define EXP2(x) exp2f(x)
#endif

typedef __attribute__((ext_vector_type(8))) __bf16 bf16x8;
typedef __attribute__((ext_vector_type(4))) float floatx4;
typedef __attribute__((ext_vector_type(8))) unsigned short ushort8;
typedef __attribute__((address_space(3))) unsigned int lds_uint;
typedef const __attribute__((address_space(1))) unsigned int g_uint;

__device__ __forceinline__ unsigned short f2bf(float f){
  union { float f; unsigned u; } v; v.f = f;
  unsigned u = v.u;
  u += 0x7fffu + ((u >> 16) & 1u);
  return (unsigned short)(u >> 16);
}
__device__ __forceinline__ unsigned short f2bf_tr(float f){   // truncating (P >= 0, softmax-internal)
  union { float f; unsigned u; } v; v.f = f;
  return (unsigned short)(v.u >> 16);
}

// ---------------- prep kernel 1: x -> bf16 (blocks 0..4095) + qbias build (blocks 4096..4107) ----------------
__global__ void k_cvt_qb(const float* __restrict__ x, unsigned short* __restrict__ xb,
                         const float* __restrict__ bq, const float* __restrict__ bk,
                         const float* __restrict__ bv, float* __restrict__ qbias){
  const int bid = blockIdx.x, t = threadIdx.x;
  if (bid < 4096){
    int i = (bid * 256 + t) * 4;
    float4 v = *(const float4*)(x + i);
    ushort4 o;
    o.x = f2bf(v.x); o.y = f2bf(v.y); o.z = f2bf(v.z); o.w = f2bf(v.w);
    *(ushort4*)(xb + i) = o;
  } else {
    int i = (bid - 4096) * 256 + t;   // 0..3071
    qbias[i] = (i < 1024) ? bq[i] * QSCL : (i < 2048) ? bk[i - 1024] : bv[i - 2048];
  }
}

// ---------------- prep kernel 2: all weight transposes (block-uniform branches) ----------------
// bid <1024: Wo[1024][1024]->wot | <3072: W1[1024][2048]->w1t | <5120: W2[2048][1024]->w2t
// | <8192: Wq/Wk/Wv [16][1024][64] -> fused wqkvt [3072][1024] (Wq pre-scaled QSCL)
__global__ void __launch_bounds__(256) k_prep_w(const float* __restrict__ Wo, const float* __restrict__ W1,
                                                const float* __restrict__ W2, const float* __restrict__ Wq,
                                                const float* __restrict__ Wk, const float* __restrict__ Wv,
                                                unsigned short* __restrict__ wot, unsigned short* __restrict__ w1t,
                                                unsigned short* __restrict__ w2t, unsigned short* __restrict__ wqkvt){
  __shared__ unsigned short Ts[32 * 36];
  const int t = threadIdx.x, bid = blockIdx.x;
  const int lr = t >> 3, lc4 = (t & 7) << 2;
  if (bid >= 5120){
    const int id = bid - 5120;                  // [0,3072)
    const int xm = id & 31, yd = (id >> 5) & 1, z = id >> 6;   // z in [0,48)
    const int tensor = z >> 4, h = z & 15;
    const float* W = (tensor == 0) ? Wq : (tensor == 1) ? Wk : Wv;
    const float scl = (tensor == 0) ? QSCL : 1.0f;
    const int m0 = xm << 5, d0 = yd << 5;
    float4 v = *(const float4*)(W + ((size_t)h << 16) + (size_t)(m0 + lr) * 64 + d0 + lc4);
    ushort4 o; o.x = f2bf(v.x * scl); o.y = f2bf(v.y * scl); o.z = f2bf(v.z * scl); o.w = f2bf(v.w * scl);
    *(ushort4*)&Ts[lr * 36 + lc4] = o;
    __syncthreads();
    ushort4 w;
    w.x = Ts[(lc4 + 0) * 36 + lr];
    w.y = Ts[(lc4 + 1) * 36 + lr];
    w.z = Ts[(lc4 + 2) * 36 + lr];
    w.w = Ts[(lc4 + 3) * 36 + lr];
    const int n = (tensor << 10) + (h << 6) + d0 + lr;
    *(ushort4*)(wqkvt + ((size_t)n << 10) + m0 + lc4) = w;
    return;
  }
  const float* src; unsigned short* dst; int K, N, k0, n0;
  if (bid < 1024){
    src = Wo; dst = wot; K = 1024; N = 1024;
    n0 = (bid & 31) << 5; k0 = (bid >> 5) << 5;
  } else if (bid < 3072){
    const int id = bid - 1024;
    src = W1; dst = w1t; K = 1024; N = 2048;
    n0 = (id & 63) << 5; k0 = (id >> 6) << 5;
  } else {
    const int id = bid - 3072;
    src = W2; dst = w2t; K = 2048; N = 1024;
    n0 = (id & 31) << 5; k0 = (id >> 5) << 5;
  }
  float4 v = *(const float4*)(src + (size_t)(k0 + lr) * N + n0 + lc4);
  ushort4 o; o.x = f2bf(v.x); o.y = f2bf(v.y); o.z = f2bf(v.z); o.w = f2bf(v.w);
  *(ushort4*)&Ts[lr * 36 + lc4] = o;
  __syncthreads();
  ushort4 w;
  w.x = Ts[(lc4 + 0) * 36 + lr];
  w.y = Ts[(lc4 + 1) * 36 + lr];
  w.z = Ts[(lc4 + 2) * 36 + lr];
  w.w = Ts[(lc4 + 3) * 36 + lr];
  *(ushort4*)(dst + (size_t)(n0 + lr) * K + k0 + lc4) = w;
}

// ---------------- bf16 MFMA GEMM v3, 128x128 tile, BK=32, double-buffered LDS ----------------
// v2 post-mortem: BK=64 dbuf = 64 KB LDS -> 2 blocks/CU; QKV's 768 blocks went lumpy (1.5 rounds),
// eating the pipeline gain. v3: BK=32 dbuf = 32 KB LDS -> 3 blocks/CU (launch_bounds(256,3));
// QKV returns to the exact 768=3x256 single-round schedule WITH prefetch-before-compute.
// Per step: 4 gload_lds + 8 ds_read_b128 + 16 MFMA + 1 barrier; drain hidden by compute + 3-block TLP.
template<int RELU, int OUTBF>
__global__ void __launch_bounds__(256, 3) k_gemm128(const unsigned short* __restrict__ A,
                                                 const unsigned short* __restrict__ Bt,
                                                 const float* __restrict__ bias,
                                                 void* __restrict__ Cout, int N, int K){
  __shared__ unsigned short As[2][128 * 32];
  __shared__ unsigned short Bs[2][128 * 32];
  const int t = threadIdx.x;
  const int m0 = blockIdx.y << 7, n0 = blockIdx.x << 7;
  const int lane = t & 63, w = t >> 6;
  const int quad = lane >> 4, l16 = lane & 15;
  const int mw = (w & 1) << 6, nw = (w >> 1) << 6;
  floatx4 acc[4][4];
  #pragma unroll
  for (int i = 0; i < 4; i++)
    #pragma unroll
    for (int j = 0; j < 4; j++) acc[i][j] = (floatx4){0.f, 0.f, 0.f, 0.f};
  const unsigned short* Ag  = A  + (size_t)(m0 + (t >> 2)) * K + ((t & 3) << 3);
  const unsigned short* Ag2 = Ag + (size_t)64 * K;
  const unsigned short* Bg  = Bt + (size_t)(n0 + (t >> 2)) * K + ((t & 3) << 3);
  const unsigned short* Bg2 = Bg + (size_t)64 * K;

#define STG128(Ad, Bd, kb) { \
    __builtin_amdgcn_global_load_lds((g_uint*)(Ag  + (kb)), (lds_uint*)&(Ad)[t << 3],          16, 0, 0); \
    __builtin_amdgcn_global_load_lds((g_uint*)(Ag2 + (kb)), (lds_uint*)&(Ad)[(t << 3) + 2048], 16, 0, 0); \
    __builtin_amdgcn_global_load_lds((g_uint*)(Bg  + (kb)), (lds_uint*)&(Bd)[t << 3],          16, 0, 0); \
    __builtin_amdgcn_global_load_lds((g_uint*)(Bg2 + (kb)), (lds_uint*)&(Bd)[(t << 3) + 2048], 16, 0, 0); \
  }

  STG128(As[0], Bs[0], 0);
  __syncthreads();
  int cur = 0;
  for (int kb = 0; kb < K; kb += 32){
    if (kb + 32 < K) STG128(As[cur ^ 1], Bs[cur ^ 1], kb + 32);
    const unsigned short* Ar = As[cur];
    const unsigned short* Br = Bs[cur];
    bf16x8 af[4], bf[4];
    #pragma unroll
    for (int mt = 0; mt < 4; mt++)
      af[mt] = *(const bf16x8*)&Ar[((mw + (mt << 4) + l16) << 5) + (quad << 3)];
    #pragma unroll
    for (int nt = 0; nt < 4; nt++)
      bf[nt] = *(const bf16x8*)&Br[((nw + (nt << 4) + l16) << 5) + (quad << 3)];
    #pragma unroll
    for (int mt = 0; mt < 4; mt++)
      #pragma unroll
      for (int nt = 0; nt < 4; nt++)
        acc[mt][nt] = __builtin_amdgcn_mfma_f32_16x16x32_bf16(af[mt], bf[nt], acc[mt][nt], 0, 0, 0);
    __syncthreads();
    cur ^= 1;
  }
#undef STG128
  #pragma unroll
  for (int nt = 0; nt < 4; nt++){
    const int col = n0 + nw + (nt << 4) + l16;
    const float bsv = bias[col];
    #pragma unroll
    for (int mt = 0; mt < 4; mt++){
      const int row = m0 + mw + (mt << 4) + (quad << 2);
      #pragma unroll
      for (int r = 0; r < 4; r++){
        float v = acc[mt][nt][r] + bsv;
        if (RELU) v = fmaxf(v, 0.f);
        if (OUTBF) ((unsigned short*)Cout)[(size_t)(row + r) * N + col] = f2bf(v);
        else       ((float*)Cout)[(size_t)(row + r) * N + col] = v;
      }
    }
  }
}

// ---------------- bf16 MFMA GEMM v2, 128x64 tile, BK=64, double-buffered LDS (Wo/FFN2) ----------------
// Same T3-minimum restructure as k_gemm128 v2. LDS 48 KB; grid-limited at 2 blocks/CU anyway.
template<int RELU, int OUTBF>
__global__ void __launch_bounds__(256) k_gemm64n(const unsigned short* __restrict__ A,
                                                 const unsigned short* __restrict__ Bt,
                                                 const float* __restrict__ bias,
                                                 void* __restrict__ Cout, int N, int K){
  __shared__ unsigned short As[2][2 * 128 * 32];
  __shared__ unsigned short Bs[2][2 * 64 * 32];
  const int t = threadIdx.x;
  const int m0 = blockIdx.y << 7, n0 = blockIdx.x << 6;
  const int lane = t & 63, w = t >> 6;
  const int quad = lane >> 4, l16 = lane & 15;
  const int mw = (w & 1) << 6, nw = (w >> 1) << 5;
  floatx4 acc[4][2];
  #pragma unroll
  for (int i = 0; i < 4; i++)
    #pragma unroll
    for (int j = 0; j < 2; j++) acc[i][j] = (floatx4){0.f, 0.f, 0.f, 0.f};
  const unsigned short* Ag  = A  + (size_t)(m0 + (t >> 2)) * K + ((t & 3) << 3);
  const unsigned short* Ag2 = Ag + (size_t)64 * K;
  const unsigned short* Bg  = Bt + (size_t)(n0 + (t >> 2)) * K + ((t & 3) << 3);

#define STG64(Ad, Bd, kb) { \
    _Pragma("unroll") \
    for (int s = 0; s < 2; s++){ \
      const int ko = (kb) + (s << 5); \
      __builtin_amdgcn_global_load_lds((g_uint*)(Ag  + ko), (lds_uint*)&(Ad)[(s << 12) + (t << 3)],        16, 0, 0); \
      __builtin_amdgcn_global_load_lds((g_uint*)(Ag2 + ko), (lds_uint*)&(Ad)[(s << 12) + (t << 3) + 2048], 16, 0, 0); \
      __builtin_amdgcn_global_load_lds((g_uint*)(Bg  + ko), (lds_uint*)&(Bd)[(s << 11) + (t << 3)],        16, 0, 0); \
    } }

  STG64(As[0], Bs[0], 0);
  __syncthreads();
  int cur = 0;
  for (int kb = 0; kb < K; kb += 64){
    if (kb + 64 < K) STG64(As[cur ^ 1], Bs[cur ^ 1], kb + 64);
    const unsigned short* Ar = As[cur];
    const unsigned short* Br = Bs[cur];
    #pragma unroll
    for (int s = 0; s < 2; s++){
      bf16x8 af[4], bf[2];
      #pragma unroll
      for (int mt = 0; mt < 4; mt++)
        af[mt] = *(const bf16x8*)&Ar[(s << 12) + ((mw + (mt << 4) + l16) << 5) + (quad << 3)];
      #pragma unroll
      for (int nt = 0; nt < 2; nt++)
        bf[nt] = *(const bf16x8*)&Br[(s << 11) + ((nw + (nt << 4) + l16) << 5) + (quad << 3)];
      #pragma unroll
      for (int mt = 0; mt < 4; mt++)
        #pragma unroll
        for (int nt = 0; nt < 2; nt++)
          acc[mt][nt] = __builtin_amdgcn_mfma_f32_16x16x32_bf16(af[mt], bf[nt], acc[mt][nt], 0, 0, 0);
    }
    __syncthreads();
    cur ^= 1;
  }
#undef STG64
  #pragma unroll
  for (int nt = 0; nt < 2; nt++){
    const int col = n0 + nw + (nt << 4) + l16;
    const float bsv = bias[col];
    #pragma unroll
    for (int mt = 0; mt < 4; mt++){
      const int row = m0 + mw + (mt << 4) + (quad << 2);
      #pragma unroll
      for (int r = 0; r < 4; r++){
        float v = acc[mt][nt][r] + bsv;
        if (RELU) v = fmaxf(v, 0.f);
        if (OUTBF) ((unsigned short*)Cout)[(size_t)(row + r) * N + col] = f2bf(v);
        else       ((float*)Cout)[(size_t)(row + r) * N + col] = v;
      }
    }
  }
}

// ---------------- MFMA flash attention v10: v9 + XCD-locality swizzle ----------------
// v9 post-mortem: latency-bound (issue ~17K cy vs 120K wall). FETCH 69.7MB vs 24MB ideal = L2
// thrash: blocks sharing a head's K/V round-robin across all 8 XCDs -> each XCD L2 needs 16MB.
// v10 (T1): remap (xcd=lin&7, j=lin>>3) -> bh = xcd*4+(j>>4), qtile = j&15. Each XCD holds
// 4 (b,h) pairs: K/V 2MB + Q 1MB < 4MB L2 -> per-tile prefetch resolves in L2 (~250cy), covered
// by the compute phase instead of serializing an HBM miss at every tile's barrier drain.
__global__ void __launch_bounds__(256, 2) k_attn(const unsigned short* __restrict__ qkvb,
                                                 const int* __restrict__ amask,
                                                 unsigned short* __restrict__ ctxb){
  __shared__ __align__(16) unsigned short Ks[2][128 * AST];   // [key][d]  2x 18.4 KB
  __shared__ __align__(16) unsigned short Vt[2][64 * VST];    // [d][key'] 2x 17.4 KB
  __shared__ __align__(16) int msk[2][128];
  const int t = threadIdx.x;                 // 0..255
  const int w = t >> 6, lane = t & 63;       // w: 0..3
  const int quad = lane >> 4, l16 = lane & 15;
  // ---- XCD-locality swizzle: linear wgid -> (bh, qtile) such that each XCD owns 4 heads ----
  const int lin = (blockIdx.y << 4) | blockIdx.x;   // 0..511, grid (16,32)
  const int xcd = lin & 7, jj = lin >> 3;           // jj: 0..63
  const int bh = (xcd << 2) | (jj >> 4);            // 4 (b,h) pairs per XCD
  const int b = bh >> 4, h = bh & 15;
  const int q0 = (jj & 15) << 7;                    // 128-row q tile
  const int r0 = (w << 5) + l16;             // qc=0 row of this lane (0..127)
  const int r1 = r0 + 16;                    // qc=1 row
  const int sr = t >> 2, sc = (t & 3) << 4;  // K staging: rows sr, sr+64; 16-short chunk
  const int kg = t >> 4, dc = (t & 15) << 2; // V staging: 4-key groups kg, kg+16; 4-d chunk
  // sigma + bank-swizzle constants for V staging (keys 4kg+i -> phys col pc0+i; +64 for kg+16)
  const int swz  = (dc >> 4) & 3;                        // = (row>>4)&3, constant per thread
  const int pc0  = ((((kg & 3) | ((kg >> 3) << 2)) ^ swz) << 3) | (((kg >> 2) & 1) << 2);

  // ---- Q stage via Ks[0] (one-time) ----
  {
    const int qr = t >> 1, qc = (t & 1) << 5;
    const unsigned short* qs = qkvb + (size_t)((b << 11) + q0 + qr) * 3072 + (h << 6) + qc;
    unsigned short* qd = &Ks[0][qr * AST + qc];
    *(uint4*)(qd)      = *(const uint4*)(qs);
    *(uint4*)(qd + 8)  = *(const uint4*)(qs + 8);
    *(uint4*)(qd + 16) = *(const uint4*)(qs + 16);
    *(uint4*)(qd + 24) = *(const uint4*)(qs + 24);
  }
  __syncthreads();
  const bf16x8 qa0 = *(const bf16x8*)&Ks[0][r0 * AST + (quad << 3)];
  const bf16x8 qa1 = *(const bf16x8*)&Ks[0][r0 * AST + (quad << 3) + 32];
  const bf16x8 qb0 = *(const bf16x8*)&Ks[0][r1 * AST + (quad << 3)];
  const bf16x8 qb1 = *(const bf16x8*)&Ks[0][r1 * AST + (quad << 3) + 32];

  floatx4 accA[4], accB[4];
  #pragma unroll
  for (int i = 0; i < 4; i++){
    accA[i] = (floatx4){0.f, 0.f, 0.f, 0.f};
    accB[i] = (floatx4){0.f, 0.f, 0.f, 0.f};
  }
  float l_runA = 0.f, l_runB = 0.f;

  const unsigned short* kbase  = qkvb + (size_t)((b << 11) + sr) * 3072 + 1024 + (h << 6) + sc;
  const unsigned short* kbase2 = kbase + (size_t)64 * 3072;
  const unsigned short* vbase  = qkvb + (size_t)((b << 11) + (kg << 2)) * 3072 + 2048 + (h << 6) + dc;
  const unsigned short* vbase2 = vbase + (size_t)64 * 3072;
  const int* mbase = amask + (b << 11);

  uint4 krA, krB, krC, krD;
  ushort4 va0, va1, va2, va3, vb0, vb1, vb2, vb3;
  int mreg = 1;

#define LOADT(tt) { \
    const size_t off = (size_t)((tt) << 7) * 3072; \
    krA = *(const uint4*)(kbase + off); \
    krB = *(const uint4*)(kbase + off + 8); \
    krC = *(const uint4*)(kbase2 + off); \
    krD = *(const uint4*)(kbase2 + off + 8); \
    va0 = *(const ushort4*)(vbase + off); \
    va1 = *(const ushort4*)(vbase + off + 3072); \
    va2 = *(const ushort4*)(vbase + off + 2 * 3072); \
    va3 = *(const ushort4*)(vbase + off + 3 * 3072); \
    vb0 = *(const ushort4*)(vbase2 + off); \
    vb1 = *(const ushort4*)(vbase2 + off + 3072); \
    vb2 = *(const ushort4*)(vbase2 + off + 2 * 3072); \
    vb3 = *(const ushort4*)(vbase2 + off + 3 * 3072); \
    if (t < 128) mreg = mbase[((tt) << 7) + t]; \
  }

#define STORET(dst) { \
    unsigned short* Kd = Ks[dst]; \
    unsigned short* Vd = Vt[dst]; \
    *(uint4*)&Kd[sr * AST + sc]            = krA; \
    *(uint4*)&Kd[sr * AST + sc + 8]        = krB; \
    *(uint4*)&Kd[(sr + 64) * AST + sc]     = krC; \
    *(uint4*)&Kd[(sr + 64) * AST + sc + 8] = krD; \
    ushort4 cc; \
    cc.x = va0.x; cc.y = va1.x; cc.z = va2.x; cc.w = va3.x; *(ushort4*)&Vd[(dc + 0) * VST + pc0] = cc; \
    cc.x = va0.y; cc.y = va1.y; cc.z = va2.y; cc.w = va3.y; *(ushort4*)&Vd[(dc + 1) * VST + pc0] = cc; \
    cc.x = va0.z; cc.y = va1.z; cc.z = va2.z; cc.w = va3.z; *(ushort4*)&Vd[(dc + 2) * VST + pc0] = cc; \
    cc.x = va0.w; cc.y = va1.w; cc.z = va2.w; cc.w = va3.w; *(ushort4*)&Vd[(dc + 3) * VST + pc0] = cc; \
    cc.x = vb0.x; cc.y = vb1.x; cc.z = vb2.x; cc.w = vb3.x; *(ushort4*)&Vd[(dc + 0) * VST + pc0 + 64] = cc; \
    cc.x = vb0.y; cc.y = vb1.y; cc.z = vb2.y; cc.w = vb3.y; *(ushort4*)&Vd[(dc + 1) * VST + pc0 + 64] = cc; \
    cc.x = vb0.z; cc.y = vb1.z; cc.z = vb2.z; cc.w = vb3.z; *(ushort4*)&Vd[(dc + 2) * VST + pc0 + 64] = cc; \
    cc.x = vb0.w; cc.y = vb1.w; cc.z = vb2.w; cc.w = vb3.w; *(ushort4*)&Vd[(dc + 3) * VST + pc0 + 64] = cc; \
    if (t < 128) msk[dst][t] = mreg; \
  }

  // ---- prologue: tile0 -> buf0; issue tile1 prefetch ----
  LOADT(0);
  __syncthreads();            // Q fragment reads complete before Ks[0] overwrite
  STORET(0);
  LOADT(1);
  __syncthreads();            // buf0 staging visible

  int c = 0;
  for (int kt = 0; kt < 16; kt++){
    if (kt + 1 < 16) STORET(c ^ 1);       // write prefetched tile kt+1 into other buffer
    if (kt + 2 < 16) LOADT(kt + 2);       // issue global loads for tile kt+2
    {
      const unsigned short* Kc = Ks[c];
      const unsigned short* Vc = Vt[c];
      const int* Mc = msk[c];
      float lsA = 0.f, lsB = 0.f;
      #pragma unroll
      for (int s = 0; s < 4; s++){
        // ---- QK^T for key groups g0=2s (rows 32s..), g1=2s+1 (rows 32s+16..) ----
        const unsigned short* kp = &Kc[((s << 5) + l16) * AST + (quad << 3)];
        const bf16x8 k00 = *(const bf16x8*)(kp);
        const bf16x8 k01 = *(const bf16x8*)(kp + 32);
        const bf16x8 k10 = *(const bf16x8*)(kp + (AST << 4));
        const bf16x8 k11 = *(const bf16x8*)(kp + (AST << 4) + 32);
        floatx4 sA0 = (floatx4){0.f, 0.f, 0.f, 0.f};
        floatx4 sB0 = (floatx4){0.f, 0.f, 0.f, 0.f};
        floatx4 sA1 = (floatx4){0.f, 0.f, 0.f, 0.f};
        floatx4 sB1 = (floatx4){0.f, 0.f, 0.f, 0.f};
        __builtin_amdgcn_s_setprio(1);
        sA0 = __builtin_amdgcn_mfma_f32_16x16x32_bf16(k00, qa0, sA0, 0, 0, 0);
        sA0 = __builtin_amdgcn_mfma_f32_16x16x32_bf16(k01, qa1, sA0, 0, 0, 0);
        sB0 = __builtin_amdgcn_mfma_f32_16x16x32_bf16(k00, qb0, sB0, 0, 0, 0);
        sB0 = __builtin_amdgcn_mfma_f32_16x16x32_bf16(k01, qb1, sB0, 0, 0, 0);
        sA1 = __builtin_amdgcn_mfma_f32_16x16x32_bf16(k10, qa0, sA1, 0, 0, 0);
        sA1 = __builtin_amdgcn_mfma_f32_16x16x32_bf16(k11, qa1, sA1, 0, 0, 0);
        sB1 = __builtin_amdgcn_mfma_f32_16x16x32_bf16(k10, qb0, sB1, 0, 0, 0);
        sB1 = __builtin_amdgcn_mfma_f32_16x16x32_bf16(k11, qb1, sB1, 0, 0, 0);
        __builtin_amdgcn_s_setprio(0);
        // ---- masked exp (log2 domain) ----
        const int4 m0 = *(const int4*)&Mc[(s << 5) + (quad << 2)];
        const int4 m1 = *(const int4*)&Mc[(s << 5) + 16 + (quad << 2)];
        const float a0 = m0.x ? EXP2(sA0[0]) : 0.f;
        const float a1 = m0.y ? EXP2(sA0[1]) : 0.f;
        const float a2 = m0.z ? EXP2(sA0[2]) : 0.f;
        const float a3 = m0.w ? EXP2(sA0[3]) : 0.f;
        const float a4 = m1.x ? EXP2(sA1[0]) : 0.f;
        const float a5 = m1.y ? EXP2(sA1[1]) : 0.f;
        const float a6 = m1.z ? EXP2(sA1[2]) : 0.f;
        const float a7 = m1.w ? EXP2(sA1[3]) : 0.f;
        const float b0 = m0.x ? EXP2(sB0[0]) : 0.f;
        const float b1 = m0.y ? EXP2(sB0[1]) : 0.f;
        const float b2 = m0.z ? EXP2(sB0[2]) : 0.f;
        const float b3 = m0.w ? EXP2(sB0[3]) : 0.f;
        const float b4 = m1.x ? EXP2(sB1[0]) : 0.f;
        const float b5 = m1.y ? EXP2(sB1[1]) : 0.f;
        const float b6 = m1.z ? EXP2(sB1[2]) : 0.f;
        const float b7 = m1.w ? EXP2(sB1[3]) : 0.f;
        lsA += (a0 + a1) + (a2 + a3) + (a4 + a5) + (a6 + a7);
        lsB += (b0 + b1) + (b2 + b3) + (b4 + b5) + (b6 + b7);
        // ---- pack P fragments, lane-local by sigma: slots 0-3 <- g0 regs, 4-7 <- g1 regs ----
        ushort8 uA, uB;
        uA[0] = f2bf_tr(a0); uA[1] = f2bf_tr(a1); uA[2] = f2bf_tr(a2); uA[3] = f2bf_tr(a3);
        uA[4] = f2bf_tr(a4); uA[5] = f2bf_tr(a5); uA[6] = f2bf_tr(a6); uA[7] = f2bf_tr(a7);
        uB[0] = f2bf_tr(b0); uB[1] = f2bf_tr(b1); uB[2] = f2bf_tr(b2); uB[3] = f2bf_tr(b3);
        uB[4] = f2bf_tr(b4); uB[5] = f2bf_tr(b5); uB[6] = f2bf_tr(b6); uB[7] = f2bf_tr(b7);
        const bf16x8 pfA = __builtin_bit_cast(bf16x8, uA);
        const bf16x8 pfB = __builtin_bit_cast(bf16x8, uB);
        // ---- PV: O^T[d][q] += V^T[d][sigma(k)]*P^T[sigma(k)][q] ----
        __builtin_amdgcn_s_setprio(1);
        #pragma unroll
        for (int mt = 0; mt < 4; mt++){
          const bf16x8 vf = *(const bf16x8*)&Vc[((mt << 4) + l16) * VST + ((((s << 2) + quad) ^ mt) << 3)];
          accA[mt] = __builtin_amdgcn_mfma_f32_16x16x32_bf16(vf, pfA, accA[mt], 0, 0, 0);
          accB[mt] = __builtin_amdgcn_mfma_f32_16x16x32_bf16(vf, pfB, accB[mt], 0, 0, 0);
        }
        __builtin_amdgcn_s_setprio(0);
      }
      l_runA += lsA;
      l_runB += lsB;
    }
    __syncthreads();           // buf c readers done + buf c^1 staging visible
    c ^= 1;
  }
#undef LOADT
#undef STORET

  // ---- epilogue: deferred cross-quad l reduction, then O[q][d] = accO / l ----
  l_runA += __shfl_xor(l_runA, 16);
  l_runA += __shfl_xor(l_runA, 32);
  l_runB += __shfl_xor(l_runB, 16);
  l_runB += __shfl_xor(l_runB, 32);
  const float liA = 1.f / l_runA;
  const float liB = 1.f / l_runB;
  unsigned short* oA = ctxb + (size_t)((b << 11) + q0 + r0) * 1024 + (h << 6);
  unsigned short* oB = ctxb + (size_t)((b << 11) + q0 + r1) * 1024 + (h << 6);
  #pragma unroll
  for (int mt = 0; mt < 4; mt++){
    ushort4 o;
    o.x = f2bf(accA[mt][0] * liA);
    o.y = f2bf(accA[mt][1] * liA);
    o.z = f2bf(accA[mt][2] * liA);
    o.w = f2bf(accA[mt][3] * liA);
    *(ushort4*)&oA[(mt << 4) + (quad << 2)] = o;
    o.x = f2bf(accB[mt][0] * liB);
    o.y = f2bf(accB[mt][1] * liB);
    o.z = f2bf(accB[mt][2] * liB);
    o.w = f2bf(accB[mt][3] * liB);
    *(ushort4*)&oB[(mt << 4) + (quad << 2)] = o;
  }
}

// ---------------- residual + LayerNorm (1024 cols, one block per row); a is bf16 ----------------
__global__ void __launch_bounds__(256) k_ln(const unsigned short* __restrict__ a,
                                            const float* __restrict__ res,
                                            const float* __restrict__ gg, const float* __restrict__ bb,
                                            float* __restrict__ out, unsigned short* __restrict__ outb){
  const int row = blockIdx.x, t = threadIdx.x;
  const ushort4 au = ((const ushort4*)(a + (size_t)row * 1024))[t];
  const float4 rv = ((const float4*)(res + (size_t)row * 1024))[t];
  float4 v;
  { union { unsigned u; float f; } c;
    c.u = (unsigned)au.x << 16; v.x = c.f + rv.x;
    c.u = (unsigned)au.y << 16; v.y = c.f + rv.y;
    c.u = (unsigned)au.z << 16; v.z = c.f + rv.z;
    c.u = (unsigned)au.w << 16; v.w = c.f + rv.w; }
  float sum = v.x + v.y + v.z + v.w;
  float ss  = v.x * v.x + v.y * v.y + v.z * v.z + v.w * v.w;
  #pragma unroll
  for (int off = 32; off > 0; off >>= 1){
    sum += __shfl_down(sum, off);
    ss  += __shfl_down(ss, off);
  }
  __shared__ float red[8];
  const int w = t >> 6;
  if ((t & 63) == 0){ red[w] = sum; red[4 + w] = ss; }
  __syncthreads();
  const float S  = red[0] + red[1] + red[2] + red[3];
  const float SS = red[4] + red[5] + red[6] + red[7];
  const float mu  = S * (1.f / 1024.f);
  const float var = SS * (1.f / 1024.f) - mu * mu;
  const float rs  = rsqrtf(var + 1e-5f);
  const float4 gv = ((const float4*)gg)[t];
  const float4 bv = ((const float4*)bb)[t];
  float4 o;
  o.x = (v.x - mu) * rs * gv.x + bv.x;
  o.y = (v.y - mu) * rs * gv.y + bv.y;
  o.z = (v.z - mu) * rs * gv.z + bv.z;
  o.w = (v.w - mu) * rs * gv.w + bv.w;
  ((float4*)(out + (size_t)row * 1024))[t] = o;
  if (outb){
    ushort4 ob; ob.x = f2bf(o.x); ob.y = f2bf(o.y); ob.z = f2bf(o.z); ob.w = f2bf(o.w);
    ((ushort4*)(outb + (size_t)row * 1024))[t] = ob;
  }
}

extern "C" void kernel_launch(void* const* d_in, const int* in_sizes, int n_in,
                              void* d_out, int out_size, void* d_ws, size_t ws_size,
                              hipStream_t stream){
  const float* x     = (const float*)d_in[0];
  const int*   amask = (const int*)d_in[1];
  const float* Wq    = (const float*)d_in[2];
  const float* bq    = (const float*)d_in[3];
  const float* Wk    = (const float*)d_in[4];
  const float* bk    = (const float*)d_in[5];
  const float* Wv    = (const float*)d_in[6];
  const float* bv    = (const float*)d_in[7];
  const float* Wo    = (const float*)d_in[8];
  const float* bo    = (const float*)d_in[9];
  const float* g1    = (const float*)d_in[10];
  const float* b1    = (const float*)d_in[11];
  const float* W1    = (const float*)d_in[12];
  const float* bias1 = (const float*)d_in[13];
  const float* W2    = (const float*)d_in[14];
  const float* bias2 = (const float*)d_in[15];
  const float* g2    = (const float*)d_in[16];
  const float* b2    = (const float*)d_in[17];

  char* ws = (char*)d_ws;
  unsigned short* xb    = (unsigned short*)(ws + 0);            //  8 MB
  unsigned short* wqkvt = (unsigned short*)(ws + 8388608);      //  6 MB
  float*          qbias = (float*)         (ws + 14680064);     // 12 KB
  unsigned short* wot   = (unsigned short*)(ws + 14692352);     //  2 MB
  unsigned short* w1t   = (unsigned short*)(ws + 16789504);     //  4 MB
  unsigned short* w2t   = (unsigned short*)(ws + 20983808);     //  4 MB
  unsigned short* ctxb  = (unsigned short*)(ws + 25178112);     //  8 MB
  unsigned short* attnb = (unsigned short*)(ws + 33566720);     //  8 MB bf16 (Wo out; later FFN2 out)
  unsigned short* fbufb = attnb;
  unsigned short* qkvb  = (unsigned short*)(ws + 50343936);     // 24 MB: QKV bf16 [4096][3072]
  float*          out1  = (float*)         (ws + 50343936);     // 16 MB fp32, reuse (qkvb dead after attn)
  unsigned short* out1b = (unsigned short*)(ws + 50343936 + 25165824);  // 8 MB
  unsigned short* h1    = (unsigned short*)(ws + 50343936 + 33554432);  // 16 MB

  // --- prep (2 kernels) ---
  k_cvt_qb<<<dim3(4108), dim3(256), 0, stream>>>(x, xb, bq, bk, bv, qbias);
  k_prep_w<<<dim3(8192), dim3(256), 0, stream>>>(Wo, W1, W2, Wq, Wk, Wv, wot, w1t, w2t, wqkvt);

  // --- QKV projection -> bf16 (Q pre-scaled by 0.125*log2e via Wq/bq): 768 blocks = 3/CU exact ---
  k_gemm128<0,1><<<dim3(24, 32), dim3(256), 0, stream>>>(xb, wqkvt, qbias, qkvb, 3072, 1024);
  // --- MFMA flash attention v10: XCD-locality swizzle + in-register P + dbuf K/V ---
  k_attn<<<dim3(16, 32), dim3(256), 0, stream>>>(qkvb, amask, ctxb);
  // --- output projection: 128x64 tile, dbuf -> 512 blocks = 2/CU, bf16 out ---
  k_gemm64n<0,1><<<dim3(16, 32), dim3(256), 0, stream>>>(ctxb, wot, bo, attnb, MDIM, 1024);
  // --- LN1(attnb + x) -> out1 fp32 + out1b bf16 ---
  k_ln<<<dim3(4096), dim3(256), 0, stream>>>(attnb, x, g1, b1, out1, out1b);
  // --- FFN ---
  k_gemm128<1,1><<<dim3(16, 32), dim3(256), 0, stream>>>(out1b, w1t, bias1, h1, FFH, 1024);
  k_gemm64n<0,1><<<dim3(16, 32), dim3(256), 0, stream>>>(h1, w2t, bias2, fbufb, MDIM, 2048);
  // --- LN2(fbufb + out1) -> d_out ---
  k_ln<<<dim3(4096), dim3(256), 0, stream>>>(fbufb, out1, g2, b2, (float*)d_out, nullptr);
}